// Round 3
// baseline (423.916 us; speedup 1.0000x reference)
//
#include <hip/hip_runtime.h>

#define N_ZONE 100000
#define E_ZONE 2000000
#define N_OUT  50000
#define E_OUT  1000000
#define N_GND  50000
#define E_GND  1000000
#define HID    64
#define N_TOT   (N_ZONE + N_OUT + N_GND)     // 200000
#define E_TOTAL (E_ZONE + E_OUT + E_GND)     // 4000000

// ---- binning geometry ----
#define RANGE   2048
#define RSHIFT  11
#define NBZ     49
#define NBO     25
#define NBG     25
#define NBUCKET (NBZ + NBO + NBG)            // 99
#define SL      16                           // slices per bucket
#define CAP     49152                        // fixed bucket capacity (mean ~40.6k, sigma ~200)
#define OUT_PAD_BASE (NBZ * RANGE)           // 100352
#define GND_PAD_BASE ((NBZ + NBO) * RANGE)   // 151552
#define PAD_TOT      (NBUCKET * RANGE)       // 202752

#define CHUNK  4096
#define NCHUNK ((E_TOTAL + CHUNK - 1) / CHUNK)   // 977

// ILP batch depth for record loops
#define KUF 8

// ---- ws layout (32-bit words), no overlays ----
#define WCUR  0                               // u32 CUR[128] (bucket fill counts)
#define WREC  128                             // uint2 rec[99*CAP]
#define WPDEG (WREC + 2 * NBUCKET * CAP)      // deg[PAD_TOT] now lives here (region kept same size)
#define WPSZ  (WPDEG + NBUCKET * SL * RANGE)
#define WPSO  (WPSZ + NBZ * SL * RANGE * 2)
#define WPSG  (WPSO + NBO * SL * RANGE * 3)
#define WDINV (WPSG + NBG * SL * RANGE)
#define WYZ   (WDINV + PAD_TOT)
#define WYO   (WYZ + 2 * N_ZONE)
#define WYG   (WYO + 4 * N_OUT)
#define WUZ   (WYG + N_GND)
#define WUO   (WUZ + 2 * N_ZONE)
#define WUG   (WUO + 4 * N_OUT)
#define WTOT  (WUG + N_GND)                   // 20,567,072 words = 82.3 MB
#define FAST_WS_BYTES ((size_t)WTOT * 4)

// L1-bypassing loads (agent-scope relaxed atomic load -> global_load with L1 bypass).
// Used for the random y-gathers: no L1 locality, high L2 reuse.
__device__ __forceinline__ float ld_bypass_f32(const float* p) {
    return __hip_atomic_load(p, __ATOMIC_RELAXED, __HIP_MEMORY_SCOPE_AGENT);
}
__device__ __forceinline__ float2 ld_bypass_f2(const float* p) {
    unsigned long long v = __hip_atomic_load((const unsigned long long*)p,
                                             __ATOMIC_RELAXED, __HIP_MEMORY_SCOPE_AGENT);
    float2 r; __builtin_memcpy(&r, &v, 8); return r;
}

// K1: single-pass bin: stage chunk in LDS ordered by bucket, bump-allocate into
// fixed-CAP bucket regions, direct-lookup copy-out (bucket id staged per slot).
__global__ void k_bin(const int* __restrict__ eiz, const float* __restrict__ wz,
                      const int* __restrict__ eio, const float* __restrict__ wo,
                      const int* __restrict__ eig, const float* __restrict__ wg,
                      unsigned* __restrict__ cur, uint2* __restrict__ rec) {
    __shared__ unsigned la[CHUNK];
    __shared__ float    lw[CHUNK];
    __shared__ unsigned char lbk[CHUNK];
    __shared__ unsigned hist[NBUCKET];
    __shared__ unsigned sbase[NBUCKET + 1];
    __shared__ unsigned gbase[NBUCKET];
    int tid = threadIdx.x;
    for (int b = tid; b < NBUCKET; b += 256) hist[b] = 0;
    __syncthreads();
    int t0 = blockIdx.x * CHUNK;
    unsigned mya[CHUNK / 256], mybk[CHUNK / 256], myr[CHUNK / 256];
    float myw[CHUNK / 256];
#pragma unroll
    for (int i = 0; i < CHUNK / 256; i++) {
        int t = t0 + i * 256 + tid;
        unsigned b = 0xFFFFFFFFu;
        if (t < E_TOTAL) {
            int row, col; float w;
            if (t < E_ZONE) { row = eiz[t]; col = eiz[E_ZONE + t]; w = wz[t]; b = col >> RSHIFT; }
            else if (t < E_ZONE + E_OUT) { int e = t - E_ZONE; row = eio[e]; col = eio[E_OUT + e]; w = wo[e]; b = NBZ + (col >> RSHIFT); }
            else { int e = t - E_ZONE - E_OUT; row = eig[e]; col = eig[E_GND + e]; w = wg[e]; b = NBZ + NBO + (col >> RSHIFT); }
            mya[i] = ((unsigned)(col & (RANGE - 1)) << 17) | (unsigned)row;
            myw[i] = w;
            myr[i] = atomicAdd(&hist[b], 1u);
        }
        mybk[i] = b;
    }
    __syncthreads();
    if (tid == 0) {
        unsigned acc = 0;
        for (int b = 0; b < NBUCKET; b++) { sbase[b] = acc; acc += hist[b]; }
        sbase[NBUCKET] = acc;
    }
    __syncthreads();
    if (tid < NBUCKET)
        gbase[tid] = hist[tid] ? atomicAdd(&cur[tid], hist[tid]) : 0u;
#pragma unroll
    for (int i = 0; i < CHUNK / 256; i++) {
        if (mybk[i] < NBUCKET) {
            unsigned p = sbase[mybk[i]] + myr[i];
            la[p] = mya[i]; lw[p] = myw[i];
            lbk[p] = (unsigned char)mybk[i];
        }
    }
    __syncthreads();
    unsigned total = sbase[NBUCKET];
    unsigned p = tid;
    for (; p + 768u < total; p += 1024u) {
#pragma unroll
        for (int u = 0; u < 4; u++) {
            unsigned pp = p + 256u * u;
            unsigned b = lbk[pp];
            unsigned idx = b * CAP + gbase[b] + (pp - sbase[b]);
            rec[idx] = make_uint2(la[pp], __float_as_uint(lw[pp]));
        }
    }
    for (; p < total; p += 256u) {
        unsigned b = lbk[p];
        unsigned idx = b * CAP + gbase[b] + (p - sbase[b]);
        rec[idx] = make_uint2(la[p], __float_as_uint(lw[p]));
    }
}

// K2 (new): degree via direct fire-and-forget global atomics into the L2-resident
// padded deg array. Replaces the whole k_degp binned pass (atomic scatter-writes
// don't stall waves; no rec re-read, no 12.9 MB partial round-trip).
__global__ void k_dega(const int* __restrict__ eiz, const float* __restrict__ wz,
                       const int* __restrict__ eio, const float* __restrict__ wo,
                       const int* __restrict__ eig, const float* __restrict__ wg,
                       float* __restrict__ deg) {
    int g = blockIdx.x * blockDim.x + threadIdx.x;   // one thread = 4 edges
    const int GZ = E_ZONE / 4, GO = GZ + E_OUT / 4, GG = GO + E_GND / 4;
    int4 c4; float4 w4; int base;
    if (g < GZ) {
        c4 = ((const int4*)(eiz + E_ZONE))[g];
        w4 = ((const float4*)wz)[g];
        base = 0;
    } else if (g < GO) {
        int e = g - GZ;
        c4 = ((const int4*)(eio + E_OUT))[e];
        w4 = ((const float4*)wo)[e];
        base = OUT_PAD_BASE;
    } else if (g < GG) {
        int e = g - GO;
        c4 = ((const int4*)(eig + E_GND))[e];
        w4 = ((const float4*)wg)[e];
        base = GND_PAD_BASE;
    } else return;
    atomicAdd(deg + base + c4.x, w4.x);
    atomicAdd(deg + base + c4.y, w4.y);
    atomicAdd(deg + base + c4.z, w4.z);
    atomicAdd(deg + base + c4.w, w4.w);
}

// K3: deg -> dinv; y = dinv * x (deg now a single dense array, not 16 slices)
__global__ void k_dinvy(const float* __restrict__ xz, const float* __restrict__ xo,
                        const float* __restrict__ xg, float* __restrict__ ws) {
    int p = blockIdx.x * blockDim.x + threadIdx.x;
    if (p >= PAD_TOT) return;
    float d = 1.0f + ws[WPDEG + p];
    float di = rsqrtf(d);
    ws[WDINV + p] = di;
    if (p < OUT_PAD_BASE) {
        if (p < N_ZONE) {
            ws[WYZ + 2 * p]     = di * xz[2 * p];
            ws[WYZ + 2 * p + 1] = di * xz[2 * p + 1];
        }
    } else if (p < GND_PAD_BASE) {
        int idx = p - OUT_PAD_BASE;
        if (idx < N_OUT) {
            ws[WYO + 4 * idx]     = di * xo[3 * idx];
            ws[WYO + 4 * idx + 1] = di * xo[3 * idx + 1];
            ws[WYO + 4 * idx + 2] = di * xo[3 * idx + 2];
            ws[WYO + 4 * idx + 3] = 0.0f;
        }
    } else {
        int idx = p - GND_PAD_BASE;
        if (idx < N_GND) ws[WYG + idx] = di * xg[idx];
    }
}

// K4: per (bucket, slice): LDS-accumulate s[col][ch] += w*y[row][ch].
// y-gathers now bypass L1 (agent-scope loads): tests the scattered-transaction
// throughput theory — y has no L1 locality but full L2 residency.
__global__ void k_sp(float* __restrict__ ws) {
    __shared__ __align__(16) float s[RANGE * 3];     // 24 KB
    int r = blockIdx.x / SL, sl = blockIdx.x % SL, tid = threadIdx.x;
    const unsigned* cur = (const unsigned*)(ws + WCUR);
    const uint2* rec = (const uint2*)(ws + WREC);
    int ch, rg; size_t yoff, psoff;
    if (r < NBZ)            { ch = 2; rg = r;             yoff = WYZ; psoff = WPSZ; }
    else if (r < NBZ + NBO) { ch = 3; rg = r - NBZ;       yoff = WYO; psoff = WPSO; }
    else                    { ch = 1; rg = r - NBZ - NBO; yoff = WYG; psoff = WPSG; }
    int tot = RANGE * ch;
    for (int i = tid; i < tot; i += 256) s[i] = 0.0f;
    __syncthreads();
    unsigned c = cur[r];
    size_t b0 = (size_t)r * CAP;
    unsigned per = (c + SL - 1) / SL;
    unsigned s0 = sl * per, s1 = s0 + per; if (s1 > c) s1 = c;
    if (ch == 2) {
        const float* y = ws + yoff;
        unsigned j = s0 + tid;
        for (; j + 256u * (KUF - 1) < s1; j += 256u * KUF) {
            uint2 q[KUF];
#pragma unroll
            for (int u = 0; u < KUF; u++) q[u] = rec[b0 + j + 256u * u];
            float2 yv[KUF];
#pragma unroll
            for (int u = 0; u < KUF; u++) yv[u] = ld_bypass_f2(y + 2 * (q[u].x & 0x1FFFFu));
#pragma unroll
            for (int u = 0; u < KUF; u++) {
                unsigned colr = (q[u].x >> 17) & (RANGE - 1);
                float w = __uint_as_float(q[u].y);
                atomicAdd(&s[colr * 2],     w * yv[u].x);
                atomicAdd(&s[colr * 2 + 1], w * yv[u].y);
            }
        }
        if (j < s1) {
            uint2 q[KUF];
#pragma unroll
            for (int u = 0; u < KUF; u++) {
                unsigned jj = j + 256u * u;
                q[u] = rec[b0 + (jj < s1 ? jj : j)];
            }
            float2 yv[KUF];
#pragma unroll
            for (int u = 0; u < KUF; u++) yv[u] = ld_bypass_f2(y + 2 * (q[u].x & 0x1FFFFu));
#pragma unroll
            for (int u = 0; u < KUF; u++)
                if (j + 256u * u < s1) {
                    unsigned colr = (q[u].x >> 17) & (RANGE - 1);
                    float w = __uint_as_float(q[u].y);
                    atomicAdd(&s[colr * 2],     w * yv[u].x);
                    atomicAdd(&s[colr * 2 + 1], w * yv[u].y);
                }
        }
    } else if (ch == 3) {
        const float* y = ws + yoff;
        unsigned j = s0 + tid;
        for (; j + 256u * (KUF - 1) < s1; j += 256u * KUF) {
            uint2 q[KUF];
#pragma unroll
            for (int u = 0; u < KUF; u++) q[u] = rec[b0 + j + 256u * u];
            float2 ylo[KUF], yhi[KUF];
#pragma unroll
            for (int u = 0; u < KUF; u++) {
                unsigned row = q[u].x & 0x1FFFFu;
                ylo[u] = ld_bypass_f2(y + 4 * row);
                yhi[u] = ld_bypass_f2(y + 4 * row + 2);
            }
#pragma unroll
            for (int u = 0; u < KUF; u++) {
                unsigned colr = (q[u].x >> 17) & (RANGE - 1);
                float w = __uint_as_float(q[u].y);
                atomicAdd(&s[colr * 3],     w * ylo[u].x);
                atomicAdd(&s[colr * 3 + 1], w * ylo[u].y);
                atomicAdd(&s[colr * 3 + 2], w * yhi[u].x);
            }
        }
        if (j < s1) {
            uint2 q[KUF];
#pragma unroll
            for (int u = 0; u < KUF; u++) {
                unsigned jj = j + 256u * u;
                q[u] = rec[b0 + (jj < s1 ? jj : j)];
            }
            float2 ylo[KUF], yhi[KUF];
#pragma unroll
            for (int u = 0; u < KUF; u++) {
                unsigned row = q[u].x & 0x1FFFFu;
                ylo[u] = ld_bypass_f2(y + 4 * row);
                yhi[u] = ld_bypass_f2(y + 4 * row + 2);
            }
#pragma unroll
            for (int u = 0; u < KUF; u++)
                if (j + 256u * u < s1) {
                    unsigned colr = (q[u].x >> 17) & (RANGE - 1);
                    float w = __uint_as_float(q[u].y);
                    atomicAdd(&s[colr * 3],     w * ylo[u].x);
                    atomicAdd(&s[colr * 3 + 1], w * ylo[u].y);
                    atomicAdd(&s[colr * 3 + 2], w * yhi[u].x);
                }
        }
    } else {
        const float* y = ws + yoff;
        unsigned j = s0 + tid;
        for (; j + 256u * (KUF - 1) < s1; j += 256u * KUF) {
            uint2 q[KUF];
#pragma unroll
            for (int u = 0; u < KUF; u++) q[u] = rec[b0 + j + 256u * u];
            float yv[KUF];
#pragma unroll
            for (int u = 0; u < KUF; u++) yv[u] = ld_bypass_f32(y + (q[u].x & 0x1FFFFu));
#pragma unroll
            for (int u = 0; u < KUF; u++)
                atomicAdd(&s[(q[u].x >> 17) & (RANGE - 1)], __uint_as_float(q[u].y) * yv[u]);
        }
        if (j < s1) {
            uint2 q[KUF];
#pragma unroll
            for (int u = 0; u < KUF; u++) {
                unsigned jj = j + 256u * u;
                q[u] = rec[b0 + (jj < s1 ? jj : j)];
            }
            float yv[KUF];
#pragma unroll
            for (int u = 0; u < KUF; u++) yv[u] = ld_bypass_f32(y + (q[u].x & 0x1FFFFu));
#pragma unroll
            for (int u = 0; u < KUF; u++)
                if (j + 256u * u < s1)
                    atomicAdd(&s[(q[u].x >> 17) & (RANGE - 1)], __uint_as_float(q[u].y) * yv[u]);
        }
    }
    __syncthreads();
    float* o = ws + psoff + (size_t)(rg * SL + sl) * tot;
    for (int i = tid * 4; i < tot; i += 1024)
        *(float4*)&o[i] = *(float4*)&s[i];
}

// K5: u = dinv * (y + sum_slices partial_s)
__global__ void k_u(float* __restrict__ ws) {
    int p = blockIdx.x * blockDim.x + threadIdx.x;
    if (p >= PAD_TOT) return;
    int r = p >> RSHIFT, i = p & (RANGE - 1);
    float di = ws[WDINV + p];
    if (p < OUT_PAD_BASE) {
        if (p >= N_ZONE) return;
        float s0 = ws[WYZ + 2 * p], s1 = ws[WYZ + 2 * p + 1];
#pragma unroll
        for (int sl = 0; sl < SL; sl++) {
            const float* ps = ws + WPSZ + (size_t)(r * SL + sl) * RANGE * 2;
            s0 += ps[2 * i]; s1 += ps[2 * i + 1];
        }
        ws[WUZ + 2 * p] = di * s0; ws[WUZ + 2 * p + 1] = di * s1;
    } else if (p < GND_PAD_BASE) {
        int idx = p - OUT_PAD_BASE;
        if (idx >= N_OUT) return;
        int rg = r - NBZ;
        float s0 = ws[WYO + 4 * idx], s1 = ws[WYO + 4 * idx + 1], s2 = ws[WYO + 4 * idx + 2];
#pragma unroll
        for (int sl = 0; sl < SL; sl++) {
            const float* ps = ws + WPSO + (size_t)(rg * SL + sl) * RANGE * 3;
            s0 += ps[3 * i]; s1 += ps[3 * i + 1]; s2 += ps[3 * i + 2];
        }
        ws[WUO + 4 * idx] = di * s0; ws[WUO + 4 * idx + 1] = di * s1; ws[WUO + 4 * idx + 2] = di * s2;
    } else {
        int idx = p - GND_PAD_BASE;
        if (idx >= N_GND) return;
        int rg = r - NBZ - NBO;
        float s0 = ws[WYG + idx];
#pragma unroll
        for (int sl = 0; sl < SL; sl++)
            s0 += ws[WPSG + (size_t)(rg * SL + sl) * RANGE + i];
        ws[WUG + idx] = di * s0;
    }
}

// K6: out = relu(u @ W + b), float4 stores
__global__ void k_fin2(const float* __restrict__ ws,
                       const float* __restrict__ Wz, const float* __restrict__ bz,
                       const float* __restrict__ Wo, const float* __restrict__ bo,
                       const float* __restrict__ Wg, const float* __restrict__ bg,
                       float* __restrict__ out) {
    int t = blockIdx.x * blockDim.x + threadIdx.x;
    const int TZ4 = N_ZONE * 16, TO4 = TZ4 + N_OUT * 16, TG4 = TO4 + N_GND * 16;
    if (t < TZ4) {
        int i = t >> 4, jb = (t & 15) << 2;
        float u0 = ws[WUZ + 2 * i], u1 = ws[WUZ + 2 * i + 1];
        float4 w0 = *(const float4*)(Wz + jb);
        float4 w1 = *(const float4*)(Wz + HID + jb);
        float4 bv = *(const float4*)(bz + jb);
        float4 o;
        o.x = fmaxf(bv.x + u0 * w0.x + u1 * w1.x, 0.0f);
        o.y = fmaxf(bv.y + u0 * w0.y + u1 * w1.y, 0.0f);
        o.z = fmaxf(bv.z + u0 * w0.z + u1 * w1.z, 0.0f);
        o.w = fmaxf(bv.w + u0 * w0.w + u1 * w1.w, 0.0f);
        *(float4*)(out + i * HID + jb) = o;
    } else if (t < TO4) {
        int q = t - TZ4;
        int i = q >> 4, jb = (q & 15) << 2;
        const float* u = ws + WUO + 4 * i;
        float u0 = u[0], u1 = u[1], u2 = u[2];
        float4 w0 = *(const float4*)(Wo + jb);
        float4 w1 = *(const float4*)(Wo + HID + jb);
        float4 w2 = *(const float4*)(Wo + 2 * HID + jb);
        float4 bv = *(const float4*)(bo + jb);
        float4 o;
        o.x = fmaxf(bv.x + u0 * w0.x + u1 * w1.x + u2 * w2.x, 0.0f);
        o.y = fmaxf(bv.y + u0 * w0.y + u1 * w1.y + u2 * w2.y, 0.0f);
        o.z = fmaxf(bv.z + u0 * w0.z + u1 * w1.z + u2 * w2.z, 0.0f);
        o.w = fmaxf(bv.w + u0 * w0.w + u1 * w1.w + u2 * w2.w, 0.0f);
        *(float4*)(out + N_ZONE * HID + i * HID + jb) = o;
    } else if (t < TG4) {
        int q = t - TO4;
        int i = q >> 4, jb = (q & 15) << 2;
        float u0 = ws[WUG + i];
        float4 w0 = *(const float4*)(Wg + jb);
        float4 bv = *(const float4*)(bg + jb);
        float4 o;
        o.x = fmaxf(bv.x + u0 * w0.x, 0.0f);
        o.y = fmaxf(bv.y + u0 * w0.y, 0.0f);
        o.z = fmaxf(bv.z + u0 * w0.z, 0.0f);
        o.w = fmaxf(bv.w + u0 * w0.w, 0.0f);
        *(float4*)(out + (N_ZONE + N_OUT) * HID + i * HID + jb) = o;
    }
}

// ---------------- fallback path (proven R1 kernels, 2.4 MB ws) ----------------
#define F_DEG_Z   0
#define F_DEG_O   (N_ZONE)
#define F_DEG_G   (N_ZONE + N_OUT)
#define F_DEG_TOT N_TOT
#define F_S_Z     F_DEG_TOT
#define F_S_O     (F_S_Z + N_ZONE * 2)
#define F_S_G     (F_S_O + N_OUT * 3)
#define F_TOT     (F_S_G + N_GND * 1)

__global__ void f_init(float* __restrict__ ws) {
    int i = blockIdx.x * blockDim.x + threadIdx.x;
    if (i < F_TOT) ws[i] = (i < F_DEG_TOT) ? 1.0f : 0.0f;
}
__global__ void f_deg(const int* __restrict__ eiz, const float* __restrict__ wz,
                      const int* __restrict__ eio, const float* __restrict__ wo,
                      const int* __restrict__ eig, const float* __restrict__ wg,
                      float* __restrict__ ws) {
    int t = blockIdx.x * blockDim.x + threadIdx.x;
    if (t < E_ZONE) atomicAdd(ws + F_DEG_Z + eiz[E_ZONE + t], wz[t]);
    else if (t < E_ZONE + E_OUT) { int e = t - E_ZONE; atomicAdd(ws + F_DEG_O + eio[E_OUT + e], wo[e]); }
    else if (t < E_ZONE + E_OUT + E_GND) { int e = t - E_ZONE - E_OUT; atomicAdd(ws + F_DEG_G + eig[E_GND + e], wg[e]); }
}
__global__ void f_dinv(float* __restrict__ ws) {
    int i = blockIdx.x * blockDim.x + threadIdx.x;
    if (i < F_DEG_TOT) ws[i] = 1.0f / sqrtf(ws[i]);
}
__global__ void f_scatter(const int* __restrict__ eiz, const float* __restrict__ wz, const float* __restrict__ xz,
                          const int* __restrict__ eio, const float* __restrict__ wo, const float* __restrict__ xo,
                          const int* __restrict__ eig, const float* __restrict__ wg, const float* __restrict__ xg,
                          float* __restrict__ ws) {
    int t = blockIdx.x * blockDim.x + threadIdx.x;
    if (t < E_ZONE) {
        int row = eiz[t], col = eiz[E_ZONE + t];
        float n = ws[F_DEG_Z + row] * wz[t] * ws[F_DEG_Z + col];
        atomicAdd(ws + F_S_Z + col * 2 + 0, n * xz[row * 2 + 0]);
        atomicAdd(ws + F_S_Z + col * 2 + 1, n * xz[row * 2 + 1]);
    } else if (t < E_ZONE + E_OUT) {
        int e = t - E_ZONE;
        int row = eio[e], col = eio[E_OUT + e];
        float n = ws[F_DEG_O + row] * wo[e] * ws[F_DEG_O + col];
        atomicAdd(ws + F_S_O + col * 3 + 0, n * xo[row * 3 + 0]);
        atomicAdd(ws + F_S_O + col * 3 + 1, n * xo[row * 3 + 1]);
        atomicAdd(ws + F_S_O + col * 3 + 2, n * xo[row * 3 + 2]);
    } else if (t < E_ZONE + E_OUT + E_GND) {
        int e = t - E_ZONE - E_OUT;
        int row = eig[e], col = eig[E_GND + e];
        float n = ws[F_DEG_G + row] * wg[e] * ws[F_DEG_G + col];
        atomicAdd(ws + F_S_G + col, n * xg[row]);
    }
}
__global__ void f_final(const float* __restrict__ ws,
                        const float* __restrict__ xz, const float* __restrict__ Wz, const float* __restrict__ bz,
                        const float* __restrict__ xo, const float* __restrict__ Wo, const float* __restrict__ bo,
                        const float* __restrict__ xg, const float* __restrict__ Wg, const float* __restrict__ bg,
                        float* __restrict__ out) {
    int t = blockIdx.x * blockDim.x + threadIdx.x;
    const int TZ = N_ZONE * HID, TO = TZ + N_OUT * HID, TG = TO + N_GND * HID;
    if (t < TZ) {
        int i = t >> 6, j = t & 63;
        float di = ws[F_DEG_Z + i], d2 = di * di;
        float t0 = ws[F_S_Z + i * 2 + 0] + d2 * xz[i * 2 + 0];
        float t1 = ws[F_S_Z + i * 2 + 1] + d2 * xz[i * 2 + 1];
        out[t] = fmaxf(bz[j] + t0 * Wz[j] + t1 * Wz[HID + j], 0.0f);
    } else if (t < TO) {
        int u = t - TZ;
        int i = u >> 6, j = u & 63;
        float di = ws[F_DEG_O + i], d2 = di * di;
        float t0 = ws[F_S_O + i * 3 + 0] + d2 * xo[i * 3 + 0];
        float t1 = ws[F_S_O + i * 3 + 1] + d2 * xo[i * 3 + 1];
        float t2 = ws[F_S_O + i * 3 + 2] + d2 * xo[i * 3 + 2];
        out[t] = fmaxf(bo[j] + t0 * Wo[j] + t1 * Wo[HID + j] + t2 * Wo[2 * HID + j], 0.0f);
    } else if (t < TG) {
        int u = t - TO;
        int i = u >> 6, j = u & 63;
        float di = ws[F_DEG_G + i], d2 = di * di;
        float t0 = ws[F_S_G + i] + d2 * xg[i];
        out[t] = fmaxf(bg[j] + t0 * Wg[j], 0.0f);
    }
}

extern "C" void kernel_launch(void* const* d_in, const int* in_sizes, int n_in,
                              void* d_out, int out_size, void* d_ws, size_t ws_size,
                              hipStream_t stream) {
    const float* xz = (const float*)d_in[0];
    const float* xo = (const float*)d_in[1];
    const float* xg = (const float*)d_in[2];
    const int*  eiz = (const int*)d_in[3];
    const int*  eio = (const int*)d_in[4];
    const int*  eig = (const int*)d_in[5];
    const float* Wz = (const float*)d_in[6];
    const float* Wo = (const float*)d_in[7];
    const float* Wg = (const float*)d_in[8];
    const float* bz = (const float*)d_in[9];
    const float* bo = (const float*)d_in[10];
    const float* bg = (const float*)d_in[11];
    const float* wz = (const float*)d_in[12];
    const float* wo = (const float*)d_in[13];
    const float* wg = (const float*)d_in[14];
    float* out = (float*)d_out;
    float* ws  = (float*)d_ws;

    const int B = 256;

    if (ws_size >= FAST_WS_BYTES) {
        unsigned* cur = (unsigned*)(ws + WCUR);
        uint2* rec = (uint2*)(ws + WREC);
        hipMemsetAsync(cur, 0, 128 * 4, stream);
        hipMemsetAsync(ws + WPDEG, 0, (size_t)PAD_TOT * 4, stream);
        k_dega<<<(E_TOTAL / 4 + B - 1) / B, B, 0, stream>>>(eiz, wz, eio, wo, eig, wg, ws + WPDEG);
        k_bin<<<NCHUNK, B, 0, stream>>>(eiz, wz, eio, wo, eig, wg, cur, rec);
        k_dinvy<<<(PAD_TOT + B - 1) / B, B, 0, stream>>>(xz, xo, xg, ws);
        k_sp<<<NBUCKET * SL, B, 0, stream>>>(ws);
        k_u<<<(PAD_TOT + B - 1) / B, B, 0, stream>>>(ws);
        k_fin2<<<(N_TOT * HID / 4 + B - 1) / B, B, 0, stream>>>(ws, Wz, bz, Wo, bo, Wg, bg, out);
    } else {
        const int E_TOT = E_TOTAL, OUT_TOT = N_TOT * HID;
        f_init<<<(F_TOT + B - 1) / B, B, 0, stream>>>(ws);
        f_deg<<<(E_TOT + B - 1) / B, B, 0, stream>>>(eiz, wz, eio, wo, eig, wg, ws);
        f_dinv<<<(F_DEG_TOT + B - 1) / B, B, 0, stream>>>(ws);
        f_scatter<<<(E_TOT + B - 1) / B, B, 0, stream>>>(eiz, wz, xz, eio, wo, xo, eig, wg, xg, ws);
        f_final<<<(OUT_TOT + B - 1) / B, B, 0, stream>>>(ws, xz, Wz, bz, xo, Wo, bo, xg, Wg, bg, out);
    }
}

// Round 4
// 249.053 us; speedup vs baseline: 1.7021x; 1.7021x over previous
//
#include <hip/hip_runtime.h>

#define N_ZONE 100000
#define E_ZONE 2000000
#define N_OUT  50000
#define E_OUT  1000000
#define N_GND  50000
#define E_GND  1000000
#define HID    64
#define N_TOT   (N_ZONE + N_OUT + N_GND)     // 200000
#define E_TOTAL (E_ZONE + E_OUT + E_GND)     // 4000000

// ---- binning geometry ----
#define RANGE   2048
#define RSHIFT  11
#define NBZ     49
#define NBO     25
#define NBG     25
#define NBUCKET (NBZ + NBO + NBG)            // 99
#define SL      16                           // slices per bucket
#define CAP     49152                        // fixed bucket capacity (mean ~40.6k, sigma ~200)
#define OUT_PAD_BASE (NBZ * RANGE)           // 100352
#define GND_PAD_BASE ((NBZ + NBO) * RANGE)   // 151552
#define PAD_TOT      (NBUCKET * RANGE)       // 202752

#define CHUNK  4096
#define NCHUNK ((E_TOTAL + CHUNK - 1) / CHUNK)   // 977

// ILP batch depth for record loops
#define KUF 8

// ---- ws layout (32-bit words), no overlays ----
#define WCUR  0                               // u32 CUR[128] (bucket fill counts)
#define WREC  128                             // uint2 rec[99*CAP]
#define WPDEG (WREC + 2 * NBUCKET * CAP)      // 99*16*2048 deg partials (16 slices)
#define WPSZ  (WPDEG + NBUCKET * SL * RANGE)
#define WPSO  (WPSZ + NBZ * SL * RANGE * 2)
#define WPSG  (WPSO + NBO * SL * RANGE * 3)
#define WDINV (WPSG + NBG * SL * RANGE)
#define WYZ   (WDINV + PAD_TOT)
#define WYO   (WYZ + 2 * N_ZONE)
#define WYG   (WYO + 4 * N_OUT)
#define WUZ   (WYG + N_GND)
#define WUO   (WUZ + 2 * N_ZONE)
#define WUG   (WUO + 4 * N_OUT)
#define WTOT  (WUG + N_GND)                   // 20,567,072 words = 82.3 MB
#define FAST_WS_BYTES ((size_t)WTOT * 4)

// L1-bypassing loads (agent-scope relaxed atomic load -> L1-bypass to L2).
// Used for the random y-gathers in k_sp: no L1 locality, high L2 reuse.
__device__ __forceinline__ float ld_bypass_f32(const float* p) {
    return __hip_atomic_load(p, __ATOMIC_RELAXED, __HIP_MEMORY_SCOPE_AGENT);
}
__device__ __forceinline__ float2 ld_bypass_f2(const float* p) {
    unsigned long long v = __hip_atomic_load((const unsigned long long*)p,
                                             __ATOMIC_RELAXED, __HIP_MEMORY_SCOPE_AGENT);
    float2 r; __builtin_memcpy(&r, &v, 8); return r;
}

// K1: single-pass bin: stage chunk in LDS ordered by bucket, bump-allocate into
// fixed-CAP bucket regions, direct-lookup copy-out (bucket id staged per slot).
__global__ void k_bin(const int* __restrict__ eiz, const float* __restrict__ wz,
                      const int* __restrict__ eio, const float* __restrict__ wo,
                      const int* __restrict__ eig, const float* __restrict__ wg,
                      unsigned* __restrict__ cur, uint2* __restrict__ rec) {
    __shared__ unsigned la[CHUNK];
    __shared__ float    lw[CHUNK];
    __shared__ unsigned char lbk[CHUNK];
    __shared__ unsigned hist[NBUCKET];
    __shared__ unsigned sbase[NBUCKET + 1];
    __shared__ unsigned gbase[NBUCKET];
    int tid = threadIdx.x;
    for (int b = tid; b < NBUCKET; b += 256) hist[b] = 0;
    __syncthreads();
    int t0 = blockIdx.x * CHUNK;
    unsigned mya[CHUNK / 256], mybk[CHUNK / 256], myr[CHUNK / 256];
    float myw[CHUNK / 256];
#pragma unroll
    for (int i = 0; i < CHUNK / 256; i++) {
        int t = t0 + i * 256 + tid;
        unsigned b = 0xFFFFFFFFu;
        if (t < E_TOTAL) {
            int row, col; float w;
            if (t < E_ZONE) { row = eiz[t]; col = eiz[E_ZONE + t]; w = wz[t]; b = col >> RSHIFT; }
            else if (t < E_ZONE + E_OUT) { int e = t - E_ZONE; row = eio[e]; col = eio[E_OUT + e]; w = wo[e]; b = NBZ + (col >> RSHIFT); }
            else { int e = t - E_ZONE - E_OUT; row = eig[e]; col = eig[E_GND + e]; w = wg[e]; b = NBZ + NBO + (col >> RSHIFT); }
            mya[i] = ((unsigned)(col & (RANGE - 1)) << 17) | (unsigned)row;
            myw[i] = w;
            myr[i] = atomicAdd(&hist[b], 1u);
        }
        mybk[i] = b;
    }
    __syncthreads();
    if (tid == 0) {
        unsigned acc = 0;
        for (int b = 0; b < NBUCKET; b++) { sbase[b] = acc; acc += hist[b]; }
        sbase[NBUCKET] = acc;
    }
    __syncthreads();
    if (tid < NBUCKET)
        gbase[tid] = hist[tid] ? atomicAdd(&cur[tid], hist[tid]) : 0u;
#pragma unroll
    for (int i = 0; i < CHUNK / 256; i++) {
        if (mybk[i] < NBUCKET) {
            unsigned p = sbase[mybk[i]] + myr[i];
            la[p] = mya[i]; lw[p] = myw[i];
            lbk[p] = (unsigned char)mybk[i];
        }
    }
    __syncthreads();
    unsigned total = sbase[NBUCKET];
    unsigned p = tid;
    for (; p + 768u < total; p += 1024u) {
#pragma unroll
        for (int u = 0; u < 4; u++) {
            unsigned pp = p + 256u * u;
            unsigned b = lbk[pp];
            unsigned idx = b * CAP + gbase[b] + (pp - sbase[b]);
            rec[idx] = make_uint2(la[pp], __float_as_uint(lw[pp]));
        }
    }
    for (; p < total; p += 256u) {
        unsigned b = lbk[p];
        unsigned idx = b * CAP + gbase[b] + (p - sbase[b]);
        rec[idx] = make_uint2(la[p], __float_as_uint(lw[p]));
    }
}

// K2: per (bucket, slice): LDS-accumulate deg, write dense partial.
// (Binned path restored: R3's direct global-atomic version hit ~32x write
// amplification — scattered device-scope atomics RMW at the coherence point.)
__global__ void k_degp(const uint2* __restrict__ rec, const unsigned* __restrict__ cur,
                       float* __restrict__ pdeg) {
    __shared__ float deg[RANGE];
    int r = blockIdx.x / SL, sl = blockIdx.x % SL, tid = threadIdx.x;
    for (int i = tid; i < RANGE; i += 256) deg[i] = 0.0f;
    __syncthreads();
    unsigned c = cur[r];
    size_t b0 = (size_t)r * CAP;
    unsigned per = (c + SL - 1) / SL;
    unsigned s0 = sl * per, s1 = s0 + per; if (s1 > c) s1 = c;
    unsigned j = s0 + tid;
    for (; j + 256u * (KUF - 1) < s1; j += 256u * KUF) {
        uint2 q[KUF];
#pragma unroll
        for (int u = 0; u < KUF; u++) q[u] = rec[b0 + j + 256u * u];
#pragma unroll
        for (int u = 0; u < KUF; u++)
            atomicAdd(&deg[(q[u].x >> 17) & (RANGE - 1)], __uint_as_float(q[u].y));
    }
    if (j < s1) {
        uint2 q[KUF];
#pragma unroll
        for (int u = 0; u < KUF; u++) {
            unsigned jj = j + 256u * u;
            q[u] = rec[b0 + (jj < s1 ? jj : j)];   // predicated: clamp to a known-valid slot
        }
#pragma unroll
        for (int u = 0; u < KUF; u++)
            if (j + 256u * u < s1)
                atomicAdd(&deg[(q[u].x >> 17) & (RANGE - 1)], __uint_as_float(q[u].y));
    }
    __syncthreads();
    float* o = pdeg + (size_t)blockIdx.x * RANGE;
    for (int i = tid * 4; i < RANGE; i += 1024)
        *(float4*)&o[i] = *(float4*)&deg[i];
}

// K3: reduce deg partials -> dinv; y = dinv * x
__global__ void k_dinvy(const float* __restrict__ xz, const float* __restrict__ xo,
                        const float* __restrict__ xg, float* __restrict__ ws) {
    int p = blockIdx.x * blockDim.x + threadIdx.x;
    if (p >= PAD_TOT) return;
    int r = p >> RSHIFT, i = p & (RANGE - 1);
    float d = 1.0f;
#pragma unroll
    for (int sl = 0; sl < SL; sl++)
        d += ws[WPDEG + (size_t)(r * SL + sl) * RANGE + i];
    float di = rsqrtf(d);
    ws[WDINV + p] = di;
    if (p < OUT_PAD_BASE) {
        if (p < N_ZONE) {
            ws[WYZ + 2 * p]     = di * xz[2 * p];
            ws[WYZ + 2 * p + 1] = di * xz[2 * p + 1];
        }
    } else if (p < GND_PAD_BASE) {
        int idx = p - OUT_PAD_BASE;
        if (idx < N_OUT) {
            ws[WYO + 4 * idx]     = di * xo[3 * idx];
            ws[WYO + 4 * idx + 1] = di * xo[3 * idx + 1];
            ws[WYO + 4 * idx + 2] = di * xo[3 * idx + 2];
            ws[WYO + 4 * idx + 3] = 0.0f;
        }
    } else {
        int idx = p - GND_PAD_BASE;
        if (idx < N_GND) ws[WYG + idx] = di * xg[idx];
    }
}

// K4: per (bucket, slice): LDS-accumulate s[col][ch] += w*y[row][ch].
// y-gathers bypass L1 (agent-scope loads) — this round's clean profile is the
// A/B vs R2's 55.0 us k_sp (same kernel without bypass).
__global__ void k_sp(float* __restrict__ ws) {
    __shared__ __align__(16) float s[RANGE * 3];     // 24 KB
    int r = blockIdx.x / SL, sl = blockIdx.x % SL, tid = threadIdx.x;
    const unsigned* cur = (const unsigned*)(ws + WCUR);
    const uint2* rec = (const uint2*)(ws + WREC);
    int ch, rg; size_t yoff, psoff;
    if (r < NBZ)            { ch = 2; rg = r;             yoff = WYZ; psoff = WPSZ; }
    else if (r < NBZ + NBO) { ch = 3; rg = r - NBZ;       yoff = WYO; psoff = WPSO; }
    else                    { ch = 1; rg = r - NBZ - NBO; yoff = WYG; psoff = WPSG; }
    int tot = RANGE * ch;
    for (int i = tid; i < tot; i += 256) s[i] = 0.0f;
    __syncthreads();
    unsigned c = cur[r];
    size_t b0 = (size_t)r * CAP;
    unsigned per = (c + SL - 1) / SL;
    unsigned s0 = sl * per, s1 = s0 + per; if (s1 > c) s1 = c;
    if (ch == 2) {
        const float* y = ws + yoff;
        unsigned j = s0 + tid;
        for (; j + 256u * (KUF - 1) < s1; j += 256u * KUF) {
            uint2 q[KUF];
#pragma unroll
            for (int u = 0; u < KUF; u++) q[u] = rec[b0 + j + 256u * u];
            float2 yv[KUF];
#pragma unroll
            for (int u = 0; u < KUF; u++) yv[u] = ld_bypass_f2(y + 2 * (q[u].x & 0x1FFFFu));
#pragma unroll
            for (int u = 0; u < KUF; u++) {
                unsigned colr = (q[u].x >> 17) & (RANGE - 1);
                float w = __uint_as_float(q[u].y);
                atomicAdd(&s[colr * 2],     w * yv[u].x);
                atomicAdd(&s[colr * 2 + 1], w * yv[u].y);
            }
        }
        if (j < s1) {
            uint2 q[KUF];
#pragma unroll
            for (int u = 0; u < KUF; u++) {
                unsigned jj = j + 256u * u;
                q[u] = rec[b0 + (jj < s1 ? jj : j)];
            }
            float2 yv[KUF];
#pragma unroll
            for (int u = 0; u < KUF; u++) yv[u] = ld_bypass_f2(y + 2 * (q[u].x & 0x1FFFFu));
#pragma unroll
            for (int u = 0; u < KUF; u++)
                if (j + 256u * u < s1) {
                    unsigned colr = (q[u].x >> 17) & (RANGE - 1);
                    float w = __uint_as_float(q[u].y);
                    atomicAdd(&s[colr * 2],     w * yv[u].x);
                    atomicAdd(&s[colr * 2 + 1], w * yv[u].y);
                }
        }
    } else if (ch == 3) {
        const float* y = ws + yoff;
        unsigned j = s0 + tid;
        for (; j + 256u * (KUF - 1) < s1; j += 256u * KUF) {
            uint2 q[KUF];
#pragma unroll
            for (int u = 0; u < KUF; u++) q[u] = rec[b0 + j + 256u * u];
            float2 ylo[KUF], yhi[KUF];
#pragma unroll
            for (int u = 0; u < KUF; u++) {
                unsigned row = q[u].x & 0x1FFFFu;
                ylo[u] = ld_bypass_f2(y + 4 * row);
                yhi[u] = ld_bypass_f2(y + 4 * row + 2);
            }
#pragma unroll
            for (int u = 0; u < KUF; u++) {
                unsigned colr = (q[u].x >> 17) & (RANGE - 1);
                float w = __uint_as_float(q[u].y);
                atomicAdd(&s[colr * 3],     w * ylo[u].x);
                atomicAdd(&s[colr * 3 + 1], w * ylo[u].y);
                atomicAdd(&s[colr * 3 + 2], w * yhi[u].x);
            }
        }
        if (j < s1) {
            uint2 q[KUF];
#pragma unroll
            for (int u = 0; u < KUF; u++) {
                unsigned jj = j + 256u * u;
                q[u] = rec[b0 + (jj < s1 ? jj : j)];
            }
            float2 ylo[KUF], yhi[KUF];
#pragma unroll
            for (int u = 0; u < KUF; u++) {
                unsigned row = q[u].x & 0x1FFFFu;
                ylo[u] = ld_bypass_f2(y + 4 * row);
                yhi[u] = ld_bypass_f2(y + 4 * row + 2);
            }
#pragma unroll
            for (int u = 0; u < KUF; u++)
                if (j + 256u * u < s1) {
                    unsigned colr = (q[u].x >> 17) & (RANGE - 1);
                    float w = __uint_as_float(q[u].y);
                    atomicAdd(&s[colr * 3],     w * ylo[u].x);
                    atomicAdd(&s[colr * 3 + 1], w * ylo[u].y);
                    atomicAdd(&s[colr * 3 + 2], w * yhi[u].x);
                }
        }
    } else {
        const float* y = ws + yoff;
        unsigned j = s0 + tid;
        for (; j + 256u * (KUF - 1) < s1; j += 256u * KUF) {
            uint2 q[KUF];
#pragma unroll
            for (int u = 0; u < KUF; u++) q[u] = rec[b0 + j + 256u * u];
            float yv[KUF];
#pragma unroll
            for (int u = 0; u < KUF; u++) yv[u] = ld_bypass_f32(y + (q[u].x & 0x1FFFFu));
#pragma unroll
            for (int u = 0; u < KUF; u++)
                atomicAdd(&s[(q[u].x >> 17) & (RANGE - 1)], __uint_as_float(q[u].y) * yv[u]);
        }
        if (j < s1) {
            uint2 q[KUF];
#pragma unroll
            for (int u = 0; u < KUF; u++) {
                unsigned jj = j + 256u * u;
                q[u] = rec[b0 + (jj < s1 ? jj : j)];
            }
            float yv[KUF];
#pragma unroll
            for (int u = 0; u < KUF; u++) yv[u] = ld_bypass_f32(y + (q[u].x & 0x1FFFFu));
#pragma unroll
            for (int u = 0; u < KUF; u++)
                if (j + 256u * u < s1)
                    atomicAdd(&s[(q[u].x >> 17) & (RANGE - 1)], __uint_as_float(q[u].y) * yv[u]);
        }
    }
    __syncthreads();
    float* o = ws + psoff + (size_t)(rg * SL + sl) * tot;
    for (int i = tid * 4; i < tot; i += 1024)
        *(float4*)&o[i] = *(float4*)&s[i];
}

// K5: u = dinv * (y + sum_slices partial_s)
__global__ void k_u(float* __restrict__ ws) {
    int p = blockIdx.x * blockDim.x + threadIdx.x;
    if (p >= PAD_TOT) return;
    int r = p >> RSHIFT, i = p & (RANGE - 1);
    float di = ws[WDINV + p];
    if (p < OUT_PAD_BASE) {
        if (p >= N_ZONE) return;
        float s0 = ws[WYZ + 2 * p], s1 = ws[WYZ + 2 * p + 1];
#pragma unroll
        for (int sl = 0; sl < SL; sl++) {
            const float* ps = ws + WPSZ + (size_t)(r * SL + sl) * RANGE * 2;
            s0 += ps[2 * i]; s1 += ps[2 * i + 1];
        }
        ws[WUZ + 2 * p] = di * s0; ws[WUZ + 2 * p + 1] = di * s1;
    } else if (p < GND_PAD_BASE) {
        int idx = p - OUT_PAD_BASE;
        if (idx >= N_OUT) return;
        int rg = r - NBZ;
        float s0 = ws[WYO + 4 * idx], s1 = ws[WYO + 4 * idx + 1], s2 = ws[WYO + 4 * idx + 2];
#pragma unroll
        for (int sl = 0; sl < SL; sl++) {
            const float* ps = ws + WPSO + (size_t)(rg * SL + sl) * RANGE * 3;
            s0 += ps[3 * i]; s1 += ps[3 * i + 1]; s2 += ps[3 * i + 2];
        }
        ws[WUO + 4 * idx] = di * s0; ws[WUO + 4 * idx + 1] = di * s1; ws[WUO + 4 * idx + 2] = di * s2;
    } else {
        int idx = p - GND_PAD_BASE;
        if (idx >= N_GND) return;
        int rg = r - NBZ - NBO;
        float s0 = ws[WYG + idx];
#pragma unroll
        for (int sl = 0; sl < SL; sl++)
            s0 += ws[WPSG + (size_t)(rg * SL + sl) * RANGE + i];
        ws[WUG + idx] = di * s0;
    }
}

// K6: out = relu(u @ W + b), float4 stores
__global__ void k_fin2(const float* __restrict__ ws,
                       const float* __restrict__ Wz, const float* __restrict__ bz,
                       const float* __restrict__ Wo, const float* __restrict__ bo,
                       const float* __restrict__ Wg, const float* __restrict__ bg,
                       float* __restrict__ out) {
    int t = blockIdx.x * blockDim.x + threadIdx.x;
    const int TZ4 = N_ZONE * 16, TO4 = TZ4 + N_OUT * 16, TG4 = TO4 + N_GND * 16;
    if (t < TZ4) {
        int i = t >> 4, jb = (t & 15) << 2;
        float u0 = ws[WUZ + 2 * i], u1 = ws[WUZ + 2 * i + 1];
        float4 w0 = *(const float4*)(Wz + jb);
        float4 w1 = *(const float4*)(Wz + HID + jb);
        float4 bv = *(const float4*)(bz + jb);
        float4 o;
        o.x = fmaxf(bv.x + u0 * w0.x + u1 * w1.x, 0.0f);
        o.y = fmaxf(bv.y + u0 * w0.y + u1 * w1.y, 0.0f);
        o.z = fmaxf(bv.z + u0 * w0.z + u1 * w1.z, 0.0f);
        o.w = fmaxf(bv.w + u0 * w0.w + u1 * w1.w, 0.0f);
        *(float4*)(out + i * HID + jb) = o;
    } else if (t < TO4) {
        int q = t - TZ4;
        int i = q >> 4, jb = (q & 15) << 2;
        const float* u = ws + WUO + 4 * i;
        float u0 = u[0], u1 = u[1], u2 = u[2];
        float4 w0 = *(const float4*)(Wo + jb);
        float4 w1 = *(const float4*)(Wo + HID + jb);
        float4 w2 = *(const float4*)(Wo + 2 * HID + jb);
        float4 bv = *(const float4*)(bo + jb);
        float4 o;
        o.x = fmaxf(bv.x + u0 * w0.x + u1 * w1.x + u2 * w2.x, 0.0f);
        o.y = fmaxf(bv.y + u0 * w0.y + u1 * w1.y + u2 * w2.y, 0.0f);
        o.z = fmaxf(bv.z + u0 * w0.z + u1 * w1.z + u2 * w2.z, 0.0f);
        o.w = fmaxf(bv.w + u0 * w0.w + u1 * w1.w + u2 * w2.w, 0.0f);
        *(float4*)(out + N_ZONE * HID + i * HID + jb) = o;
    } else if (t < TG4) {
        int q = t - TO4;
        int i = q >> 4, jb = (q & 15) << 2;
        float u0 = ws[WUG + i];
        float4 w0 = *(const float4*)(Wg + jb);
        float4 bv = *(const float4*)(bg + jb);
        float4 o;
        o.x = fmaxf(bv.x + u0 * w0.x, 0.0f);
        o.y = fmaxf(bv.y + u0 * w0.y, 0.0f);
        o.z = fmaxf(bv.z + u0 * w0.z, 0.0f);
        o.w = fmaxf(bv.w + u0 * w0.w, 0.0f);
        *(float4*)(out + (N_ZONE + N_OUT) * HID + i * HID + jb) = o;
    }
}

// ---------------- fallback path (proven R1 kernels, 2.4 MB ws) ----------------
#define F_DEG_Z   0
#define F_DEG_O   (N_ZONE)
#define F_DEG_G   (N_ZONE + N_OUT)
#define F_DEG_TOT N_TOT
#define F_S_Z     F_DEG_TOT
#define F_S_O     (F_S_Z + N_ZONE * 2)
#define F_S_G     (F_S_O + N_OUT * 3)
#define F_TOT     (F_S_G + N_GND * 1)

__global__ void f_init(float* __restrict__ ws) {
    int i = blockIdx.x * blockDim.x + threadIdx.x;
    if (i < F_TOT) ws[i] = (i < F_DEG_TOT) ? 1.0f : 0.0f;
}
__global__ void f_deg(const int* __restrict__ eiz, const float* __restrict__ wz,
                      const int* __restrict__ eio, const float* __restrict__ wo,
                      const int* __restrict__ eig, const float* __restrict__ wg,
                      float* __restrict__ ws) {
    int t = blockIdx.x * blockDim.x + threadIdx.x;
    if (t < E_ZONE) atomicAdd(ws + F_DEG_Z + eiz[E_ZONE + t], wz[t]);
    else if (t < E_ZONE + E_OUT) { int e = t - E_ZONE; atomicAdd(ws + F_DEG_O + eio[E_OUT + e], wo[e]); }
    else if (t < E_ZONE + E_OUT + E_GND) { int e = t - E_ZONE - E_OUT; atomicAdd(ws + F_DEG_G + eig[E_GND + e], wg[e]); }
}
__global__ void f_dinv(float* __restrict__ ws) {
    int i = blockIdx.x * blockDim.x + threadIdx.x;
    if (i < F_DEG_TOT) ws[i] = 1.0f / sqrtf(ws[i]);
}
__global__ void f_scatter(const int* __restrict__ eiz, const float* __restrict__ wz, const float* __restrict__ xz,
                          const int* __restrict__ eio, const float* __restrict__ wo, const float* __restrict__ xo,
                          const int* __restrict__ eig, const float* __restrict__ wg, const float* __restrict__ xg,
                          float* __restrict__ ws) {
    int t = blockIdx.x * blockDim.x + threadIdx.x;
    if (t < E_ZONE) {
        int row = eiz[t], col = eiz[E_ZONE + t];
        float n = ws[F_DEG_Z + row] * wz[t] * ws[F_DEG_Z + col];
        atomicAdd(ws + F_S_Z + col * 2 + 0, n * xz[row * 2 + 0]);
        atomicAdd(ws + F_S_Z + col * 2 + 1, n * xz[row * 2 + 1]);
    } else if (t < E_ZONE + E_OUT) {
        int e = t - E_ZONE;
        int row = eio[e], col = eio[E_OUT + e];
        float n = ws[F_DEG_O + row] * wo[e] * ws[F_DEG_O + col];
        atomicAdd(ws + F_S_O + col * 3 + 0, n * xo[row * 3 + 0]);
        atomicAdd(ws + F_S_O + col * 3 + 1, n * xo[row * 3 + 1]);
        atomicAdd(ws + F_S_O + col * 3 + 2, n * xo[row * 3 + 2]);
    } else if (t < E_ZONE + E_OUT + E_GND) {
        int e = t - E_ZONE - E_OUT;
        int row = eig[e], col = eig[E_GND + e];
        float n = ws[F_DEG_G + row] * wg[e] * ws[F_DEG_G + col];
        atomicAdd(ws + F_S_G + col, n * xg[row]);
    }
}
__global__ void f_final(const float* __restrict__ ws,
                        const float* __restrict__ xz, const float* __restrict__ Wz, const float* __restrict__ bz,
                        const float* __restrict__ xo, const float* __restrict__ Wo, const float* __restrict__ bo,
                        const float* __restrict__ xg, const float* __restrict__ Wg, const float* __restrict__ bg,
                        float* __restrict__ out) {
    int t = blockIdx.x * blockDim.x + threadIdx.x;
    const int TZ = N_ZONE * HID, TO = TZ + N_OUT * HID, TG = TO + N_GND * HID;
    if (t < TZ) {
        int i = t >> 6, j = t & 63;
        float di = ws[F_DEG_Z + i], d2 = di * di;
        float t0 = ws[F_S_Z + i * 2 + 0] + d2 * xz[i * 2 + 0];
        float t1 = ws[F_S_Z + i * 2 + 1] + d2 * xz[i * 2 + 1];
        out[t] = fmaxf(bz[j] + t0 * Wz[j] + t1 * Wz[HID + j], 0.0f);
    } else if (t < TO) {
        int u = t - TZ;
        int i = u >> 6, j = u & 63;
        float di = ws[F_DEG_O + i], d2 = di * di;
        float t0 = ws[F_S_O + i * 3 + 0] + d2 * xo[i * 3 + 0];
        float t1 = ws[F_S_O + i * 3 + 1] + d2 * xo[i * 3 + 1];
        float t2 = ws[F_S_O + i * 3 + 2] + d2 * xo[i * 3 + 2];
        out[t] = fmaxf(bo[j] + t0 * Wo[j] + t1 * Wo[HID + j] + t2 * Wo[2 * HID + j], 0.0f);
    } else if (t < TG) {
        int u = t - TO;
        int i = u >> 6, j = u & 63;
        float di = ws[F_DEG_G + i], d2 = di * di;
        float t0 = ws[F_S_G + i] + d2 * xg[i];
        out[t] = fmaxf(bg[j] + t0 * Wg[j], 0.0f);
    }
}

extern "C" void kernel_launch(void* const* d_in, const int* in_sizes, int n_in,
                              void* d_out, int out_size, void* d_ws, size_t ws_size,
                              hipStream_t stream) {
    const float* xz = (const float*)d_in[0];
    const float* xo = (const float*)d_in[1];
    const float* xg = (const float*)d_in[2];
    const int*  eiz = (const int*)d_in[3];
    const int*  eio = (const int*)d_in[4];
    const int*  eig = (const int*)d_in[5];
    const float* Wz = (const float*)d_in[6];
    const float* Wo = (const float*)d_in[7];
    const float* Wg = (const float*)d_in[8];
    const float* bz = (const float*)d_in[9];
    const float* bo = (const float*)d_in[10];
    const float* bg = (const float*)d_in[11];
    const float* wz = (const float*)d_in[12];
    const float* wo = (const float*)d_in[13];
    const float* wg = (const float*)d_in[14];
    float* out = (float*)d_out;
    float* ws  = (float*)d_ws;

    const int B = 256;

    if (ws_size >= FAST_WS_BYTES) {
        unsigned* cur = (unsigned*)(ws + WCUR);
        uint2* rec = (uint2*)(ws + WREC);
        hipMemsetAsync(cur, 0, 128 * 4, stream);
        k_bin<<<NCHUNK, B, 0, stream>>>(eiz, wz, eio, wo, eig, wg, cur, rec);
        k_degp<<<NBUCKET * SL, B, 0, stream>>>(rec, cur, ws + WPDEG);
        k_dinvy<<<(PAD_TOT + B - 1) / B, B, 0, stream>>>(xz, xo, xg, ws);
        k_sp<<<NBUCKET * SL, B, 0, stream>>>(ws);
        k_u<<<(PAD_TOT + B - 1) / B, B, 0, stream>>>(ws);
        k_fin2<<<(N_TOT * HID / 4 + B - 1) / B, B, 0, stream>>>(ws, Wz, bz, Wo, bo, Wg, bg, out);
    } else {
        const int E_TOT = E_TOTAL, OUT_TOT = N_TOT * HID;
        f_init<<<(F_TOT + B - 1) / B, B, 0, stream>>>(ws);
        f_deg<<<(E_TOT + B - 1) / B, B, 0, stream>>>(eiz, wz, eio, wo, eig, wg, ws);
        f_dinv<<<(F_DEG_TOT + B - 1) / B, B, 0, stream>>>(ws);
        f_scatter<<<(E_TOT + B - 1) / B, B, 0, stream>>>(eiz, wz, xz, eio, wo, xo, eig, wg, xg, ws);
        f_final<<<(OUT_TOT + B - 1) / B, B, 0, stream>>>(ws, xz, Wz, bz, xo, Wo, bo, xg, Wg, bg, out);
    }
}

// Round 5
// 248.689 us; speedup vs baseline: 1.7046x; 1.0015x over previous
//
#include <hip/hip_runtime.h>

#define N_ZONE 100000
#define E_ZONE 2000000
#define N_OUT  50000
#define E_OUT  1000000
#define N_GND  50000
#define E_GND  1000000
#define HID    64
#define N_TOT   (N_ZONE + N_OUT + N_GND)     // 200000
#define E_TOTAL (E_ZONE + E_OUT + E_GND)     // 4000000

// ---- binning geometry ----
#define RANGE   2048
#define RSHIFT  11
#define NBZ     49
#define NBO     25
#define NBG     25
#define NBUCKET (NBZ + NBO + NBG)            // 99
#define SL      16                           // slices per bucket
#define CAP     49152                        // fixed bucket capacity (mean ~40.6k, sigma ~200)
#define OUT_PAD_BASE (NBZ * RANGE)           // 100352
#define GND_PAD_BASE ((NBZ + NBO) * RANGE)   // 151552
#define PAD_TOT      (NBUCKET * RANGE)       // 202752

#define CHUNK  4096
#define NCHUNK ((E_TOTAL + CHUNK - 1) / CHUNK)   // 977

// ILP batch depth for record loops
#define KUF 8

// ---- ws layout (32-bit words), no overlays ----
#define WCUR  0                               // u32 CUR[128] (bucket fill counts)
#define WREC  128                             // uint2 rec[99*CAP]
#define WPDEG (WREC + 2 * NBUCKET * CAP)      // 99*16*2048 deg partials (16 slices)
#define WPSZ  (WPDEG + NBUCKET * SL * RANGE)
#define WPSO  (WPSZ + NBZ * SL * RANGE * 2)
#define WPSG  (WPSO + NBO * SL * RANGE * 3)
#define WDINV (WPSG + NBG * SL * RANGE)
#define WYZ   (WDINV + PAD_TOT)
#define WYO   (WYZ + 2 * N_ZONE)
#define WYG   (WYO + 4 * N_OUT)
#define WUZ   (WYG + N_GND)
#define WUO   (WUZ + 2 * N_ZONE)
#define WUG   (WUO + 4 * N_OUT)
#define WTOT  (WUG + N_GND)                   // 20,567,072 words = 82.3 MB
#define FAST_WS_BYTES ((size_t)WTOT * 4)

// L1-bypassing loads (agent-scope relaxed atomic load -> L1-bypass to L2).
// Measured neutral (R4 A/B vs R2) — kept, harmless.
__device__ __forceinline__ float ld_bypass_f32(const float* p) {
    return __hip_atomic_load(p, __ATOMIC_RELAXED, __HIP_MEMORY_SCOPE_AGENT);
}
__device__ __forceinline__ float2 ld_bypass_f2(const float* p) {
    unsigned long long v = __hip_atomic_load((const unsigned long long*)p,
                                             __ATOMIC_RELAXED, __HIP_MEMORY_SCOPE_AGENT);
    float2 r; __builtin_memcpy(&r, &v, 8); return r;
}

// K1: single-pass bin: stage chunk in LDS ordered by bucket, bump-allocate into
// fixed-CAP bucket regions, direct-lookup copy-out (bucket id staged per slot).
__global__ void k_bin(const int* __restrict__ eiz, const float* __restrict__ wz,
                      const int* __restrict__ eio, const float* __restrict__ wo,
                      const int* __restrict__ eig, const float* __restrict__ wg,
                      unsigned* __restrict__ cur, uint2* __restrict__ rec) {
    __shared__ unsigned la[CHUNK];
    __shared__ float    lw[CHUNK];
    __shared__ unsigned char lbk[CHUNK];
    __shared__ unsigned hist[NBUCKET];
    __shared__ unsigned sbase[NBUCKET + 1];
    __shared__ unsigned gbase[NBUCKET];
    int tid = threadIdx.x;
    for (int b = tid; b < NBUCKET; b += 256) hist[b] = 0;
    __syncthreads();
    int t0 = blockIdx.x * CHUNK;
    unsigned mya[CHUNK / 256], mybk[CHUNK / 256], myr[CHUNK / 256];
    float myw[CHUNK / 256];
#pragma unroll
    for (int i = 0; i < CHUNK / 256; i++) {
        int t = t0 + i * 256 + tid;
        unsigned b = 0xFFFFFFFFu;
        if (t < E_TOTAL) {
            int row, col; float w;
            if (t < E_ZONE) { row = eiz[t]; col = eiz[E_ZONE + t]; w = wz[t]; b = col >> RSHIFT; }
            else if (t < E_ZONE + E_OUT) { int e = t - E_ZONE; row = eio[e]; col = eio[E_OUT + e]; w = wo[e]; b = NBZ + (col >> RSHIFT); }
            else { int e = t - E_ZONE - E_OUT; row = eig[e]; col = eig[E_GND + e]; w = wg[e]; b = NBZ + NBO + (col >> RSHIFT); }
            mya[i] = ((unsigned)(col & (RANGE - 1)) << 17) | (unsigned)row;
            myw[i] = w;
            myr[i] = atomicAdd(&hist[b], 1u);
        }
        mybk[i] = b;
    }
    __syncthreads();
    if (tid == 0) {
        unsigned acc = 0;
        for (int b = 0; b < NBUCKET; b++) { sbase[b] = acc; acc += hist[b]; }
        sbase[NBUCKET] = acc;
    }
    __syncthreads();
    if (tid < NBUCKET)
        gbase[tid] = hist[tid] ? atomicAdd(&cur[tid], hist[tid]) : 0u;
#pragma unroll
    for (int i = 0; i < CHUNK / 256; i++) {
        if (mybk[i] < NBUCKET) {
            unsigned p = sbase[mybk[i]] + myr[i];
            la[p] = mya[i]; lw[p] = myw[i];
            lbk[p] = (unsigned char)mybk[i];
        }
    }
    __syncthreads();
    unsigned total = sbase[NBUCKET];
    unsigned p = tid;
    for (; p + 768u < total; p += 1024u) {
#pragma unroll
        for (int u = 0; u < 4; u++) {
            unsigned pp = p + 256u * u;
            unsigned b = lbk[pp];
            unsigned idx = b * CAP + gbase[b] + (pp - sbase[b]);
            rec[idx] = make_uint2(la[pp], __float_as_uint(lw[pp]));
        }
    }
    for (; p < total; p += 256u) {
        unsigned b = lbk[p];
        unsigned idx = b * CAP + gbase[b] + (p - sbase[b]);
        rec[idx] = make_uint2(la[p], __float_as_uint(lw[p]));
    }
}

// K2: per (bucket, slice): LDS-accumulate deg, write dense partial.
__global__ void k_degp(const uint2* __restrict__ rec, const unsigned* __restrict__ cur,
                       float* __restrict__ pdeg) {
    __shared__ float deg[RANGE];
    int r = blockIdx.x / SL, sl = blockIdx.x % SL, tid = threadIdx.x;
    for (int i = tid; i < RANGE; i += 256) deg[i] = 0.0f;
    __syncthreads();
    unsigned c = cur[r];
    size_t b0 = (size_t)r * CAP;
    unsigned per = (c + SL - 1) / SL;
    unsigned s0 = sl * per, s1 = s0 + per; if (s1 > c) s1 = c;
    unsigned j = s0 + tid;
    for (; j + 256u * (KUF - 1) < s1; j += 256u * KUF) {
        uint2 q[KUF];
#pragma unroll
        for (int u = 0; u < KUF; u++) q[u] = rec[b0 + j + 256u * u];
#pragma unroll
        for (int u = 0; u < KUF; u++)
            atomicAdd(&deg[(q[u].x >> 17) & (RANGE - 1)], __uint_as_float(q[u].y));
    }
    if (j < s1) {
        uint2 q[KUF];
#pragma unroll
        for (int u = 0; u < KUF; u++) {
            unsigned jj = j + 256u * u;
            q[u] = rec[b0 + (jj < s1 ? jj : j)];   // predicated: clamp to a known-valid slot
        }
#pragma unroll
        for (int u = 0; u < KUF; u++)
            if (j + 256u * u < s1)
                atomicAdd(&deg[(q[u].x >> 17) & (RANGE - 1)], __uint_as_float(q[u].y));
    }
    __syncthreads();
    float* o = pdeg + (size_t)blockIdx.x * RANGE;
    for (int i = tid * 4; i < RANGE; i += 1024)
        *(float4*)&o[i] = *(float4*)&deg[i];
}

// K3: reduce deg partials -> dinv; y = dinv * x
__global__ void k_dinvy(const float* __restrict__ xz, const float* __restrict__ xo,
                        const float* __restrict__ xg, float* __restrict__ ws) {
    int p = blockIdx.x * blockDim.x + threadIdx.x;
    if (p >= PAD_TOT) return;
    int r = p >> RSHIFT, i = p & (RANGE - 1);
    float d = 1.0f;
#pragma unroll
    for (int sl = 0; sl < SL; sl++)
        d += ws[WPDEG + (size_t)(r * SL + sl) * RANGE + i];
    float di = rsqrtf(d);
    ws[WDINV + p] = di;
    if (p < OUT_PAD_BASE) {
        if (p < N_ZONE) {
            ws[WYZ + 2 * p]     = di * xz[2 * p];
            ws[WYZ + 2 * p + 1] = di * xz[2 * p + 1];
        }
    } else if (p < GND_PAD_BASE) {
        int idx = p - OUT_PAD_BASE;
        if (idx < N_OUT) {
            ws[WYO + 4 * idx]     = di * xo[3 * idx];
            ws[WYO + 4 * idx + 1] = di * xo[3 * idx + 1];
            ws[WYO + 4 * idx + 2] = di * xo[3 * idx + 2];
            ws[WYO + 4 * idx + 3] = 0.0f;
        }
    } else {
        int idx = p - GND_PAD_BASE;
        if (idx < N_GND) ws[WYG + idx] = di * xg[idx];
    }
}

// K4: per (bucket, slice): LDS-accumulate s += w*y[row], PLANAR channel layout.
// Old layout s[col*ch + c]: zone's per-channel atomics hit only 16 of 32 banks
// (even/odd words) -> ~4 lanes/bank. Planar s[c*RANGE + col] spreads every
// atomic over all 32 banks (~2 lanes/bank = free per m136). Only the bank
// distribution of the DS atomics changes — clean test of the conflict theory.
__global__ void k_sp(float* __restrict__ ws) {
    __shared__ __align__(16) float s[RANGE * 3];     // 24 KB
    int r = blockIdx.x / SL, sl = blockIdx.x % SL, tid = threadIdx.x;
    const unsigned* cur = (const unsigned*)(ws + WCUR);
    const uint2* rec = (const uint2*)(ws + WREC);
    int ch, rg; size_t yoff, psoff;
    if (r < NBZ)            { ch = 2; rg = r;             yoff = WYZ; psoff = WPSZ; }
    else if (r < NBZ + NBO) { ch = 3; rg = r - NBZ;       yoff = WYO; psoff = WPSO; }
    else                    { ch = 1; rg = r - NBZ - NBO; yoff = WYG; psoff = WPSG; }
    int tot = RANGE * ch;
    for (int i = tid; i < tot; i += 256) s[i] = 0.0f;
    __syncthreads();
    unsigned c = cur[r];
    size_t b0 = (size_t)r * CAP;
    unsigned per = (c + SL - 1) / SL;
    unsigned s0 = sl * per, s1 = s0 + per; if (s1 > c) s1 = c;
    if (ch == 2) {
        const float* y = ws + yoff;
        unsigned j = s0 + tid;
        for (; j + 256u * (KUF - 1) < s1; j += 256u * KUF) {
            uint2 q[KUF];
#pragma unroll
            for (int u = 0; u < KUF; u++) q[u] = rec[b0 + j + 256u * u];
            float2 yv[KUF];
#pragma unroll
            for (int u = 0; u < KUF; u++) yv[u] = ld_bypass_f2(y + 2 * (q[u].x & 0x1FFFFu));
#pragma unroll
            for (int u = 0; u < KUF; u++) {
                unsigned colr = (q[u].x >> 17) & (RANGE - 1);
                float w = __uint_as_float(q[u].y);
                atomicAdd(&s[colr],         w * yv[u].x);
                atomicAdd(&s[RANGE + colr], w * yv[u].y);
            }
        }
        if (j < s1) {
            uint2 q[KUF];
#pragma unroll
            for (int u = 0; u < KUF; u++) {
                unsigned jj = j + 256u * u;
                q[u] = rec[b0 + (jj < s1 ? jj : j)];
            }
            float2 yv[KUF];
#pragma unroll
            for (int u = 0; u < KUF; u++) yv[u] = ld_bypass_f2(y + 2 * (q[u].x & 0x1FFFFu));
#pragma unroll
            for (int u = 0; u < KUF; u++)
                if (j + 256u * u < s1) {
                    unsigned colr = (q[u].x >> 17) & (RANGE - 1);
                    float w = __uint_as_float(q[u].y);
                    atomicAdd(&s[colr],         w * yv[u].x);
                    atomicAdd(&s[RANGE + colr], w * yv[u].y);
                }
        }
    } else if (ch == 3) {
        const float* y = ws + yoff;
        unsigned j = s0 + tid;
        for (; j + 256u * (KUF - 1) < s1; j += 256u * KUF) {
            uint2 q[KUF];
#pragma unroll
            for (int u = 0; u < KUF; u++) q[u] = rec[b0 + j + 256u * u];
            float2 ylo[KUF], yhi[KUF];
#pragma unroll
            for (int u = 0; u < KUF; u++) {
                unsigned row = q[u].x & 0x1FFFFu;
                ylo[u] = ld_bypass_f2(y + 4 * row);
                yhi[u] = ld_bypass_f2(y + 4 * row + 2);
            }
#pragma unroll
            for (int u = 0; u < KUF; u++) {
                unsigned colr = (q[u].x >> 17) & (RANGE - 1);
                float w = __uint_as_float(q[u].y);
                atomicAdd(&s[colr],             w * ylo[u].x);
                atomicAdd(&s[RANGE + colr],     w * ylo[u].y);
                atomicAdd(&s[2 * RANGE + colr], w * yhi[u].x);
            }
        }
        if (j < s1) {
            uint2 q[KUF];
#pragma unroll
            for (int u = 0; u < KUF; u++) {
                unsigned jj = j + 256u * u;
                q[u] = rec[b0 + (jj < s1 ? jj : j)];
            }
            float2 ylo[KUF], yhi[KUF];
#pragma unroll
            for (int u = 0; u < KUF; u++) {
                unsigned row = q[u].x & 0x1FFFFu;
                ylo[u] = ld_bypass_f2(y + 4 * row);
                yhi[u] = ld_bypass_f2(y + 4 * row + 2);
            }
#pragma unroll
            for (int u = 0; u < KUF; u++)
                if (j + 256u * u < s1) {
                    unsigned colr = (q[u].x >> 17) & (RANGE - 1);
                    float w = __uint_as_float(q[u].y);
                    atomicAdd(&s[colr],             w * ylo[u].x);
                    atomicAdd(&s[RANGE + colr],     w * ylo[u].y);
                    atomicAdd(&s[2 * RANGE + colr], w * yhi[u].x);
                }
        }
    } else {
        const float* y = ws + yoff;
        unsigned j = s0 + tid;
        for (; j + 256u * (KUF - 1) < s1; j += 256u * KUF) {
            uint2 q[KUF];
#pragma unroll
            for (int u = 0; u < KUF; u++) q[u] = rec[b0 + j + 256u * u];
            float yv[KUF];
#pragma unroll
            for (int u = 0; u < KUF; u++) yv[u] = ld_bypass_f32(y + (q[u].x & 0x1FFFFu));
#pragma unroll
            for (int u = 0; u < KUF; u++)
                atomicAdd(&s[(q[u].x >> 17) & (RANGE - 1)], __uint_as_float(q[u].y) * yv[u]);
        }
        if (j < s1) {
            uint2 q[KUF];
#pragma unroll
            for (int u = 0; u < KUF; u++) {
                unsigned jj = j + 256u * u;
                q[u] = rec[b0 + (jj < s1 ? jj : j)];
            }
            float yv[KUF];
#pragma unroll
            for (int u = 0; u < KUF; u++) yv[u] = ld_bypass_f32(y + (q[u].x & 0x1FFFFu));
#pragma unroll
            for (int u = 0; u < KUF; u++)
                if (j + 256u * u < s1)
                    atomicAdd(&s[(q[u].x >> 17) & (RANGE - 1)], __uint_as_float(q[u].y) * yv[u]);
        }
    }
    __syncthreads();
    float* o = ws + psoff + (size_t)(rg * SL + sl) * tot;
    for (int i = tid * 4; i < tot; i += 1024)
        *(float4*)&o[i] = *(float4*)&s[i];
}

// K5: u = dinv * (y + sum_slices partial_s)  — reads match k_sp's planar layout
__global__ void k_u(float* __restrict__ ws) {
    int p = blockIdx.x * blockDim.x + threadIdx.x;
    if (p >= PAD_TOT) return;
    int r = p >> RSHIFT, i = p & (RANGE - 1);
    float di = ws[WDINV + p];
    if (p < OUT_PAD_BASE) {
        if (p >= N_ZONE) return;
        float s0 = ws[WYZ + 2 * p], s1 = ws[WYZ + 2 * p + 1];
#pragma unroll
        for (int sl = 0; sl < SL; sl++) {
            const float* ps = ws + WPSZ + (size_t)(r * SL + sl) * RANGE * 2;
            s0 += ps[i]; s1 += ps[RANGE + i];
        }
        ws[WUZ + 2 * p] = di * s0; ws[WUZ + 2 * p + 1] = di * s1;
    } else if (p < GND_PAD_BASE) {
        int idx = p - OUT_PAD_BASE;
        if (idx >= N_OUT) return;
        int rg = r - NBZ;
        float s0 = ws[WYO + 4 * idx], s1 = ws[WYO + 4 * idx + 1], s2 = ws[WYO + 4 * idx + 2];
#pragma unroll
        for (int sl = 0; sl < SL; sl++) {
            const float* ps = ws + WPSO + (size_t)(rg * SL + sl) * RANGE * 3;
            s0 += ps[i]; s1 += ps[RANGE + i]; s2 += ps[2 * RANGE + i];
        }
        ws[WUO + 4 * idx] = di * s0; ws[WUO + 4 * idx + 1] = di * s1; ws[WUO + 4 * idx + 2] = di * s2;
    } else {
        int idx = p - GND_PAD_BASE;
        if (idx >= N_GND) return;
        int rg = r - NBZ - NBO;
        float s0 = ws[WYG + idx];
#pragma unroll
        for (int sl = 0; sl < SL; sl++)
            s0 += ws[WPSG + (size_t)(rg * SL + sl) * RANGE + i];
        ws[WUG + idx] = di * s0;
    }
}

// K6: out = relu(u @ W + b), float4 stores
__global__ void k_fin2(const float* __restrict__ ws,
                       const float* __restrict__ Wz, const float* __restrict__ bz,
                       const float* __restrict__ Wo, const float* __restrict__ bo,
                       const float* __restrict__ Wg, const float* __restrict__ bg,
                       float* __restrict__ out) {
    int t = blockIdx.x * blockDim.x + threadIdx.x;
    const int TZ4 = N_ZONE * 16, TO4 = TZ4 + N_OUT * 16, TG4 = TO4 + N_GND * 16;
    if (t < TZ4) {
        int i = t >> 4, jb = (t & 15) << 2;
        float u0 = ws[WUZ + 2 * i], u1 = ws[WUZ + 2 * i + 1];
        float4 w0 = *(const float4*)(Wz + jb);
        float4 w1 = *(const float4*)(Wz + HID + jb);
        float4 bv = *(const float4*)(bz + jb);
        float4 o;
        o.x = fmaxf(bv.x + u0 * w0.x + u1 * w1.x, 0.0f);
        o.y = fmaxf(bv.y + u0 * w0.y + u1 * w1.y, 0.0f);
        o.z = fmaxf(bv.z + u0 * w0.z + u1 * w1.z, 0.0f);
        o.w = fmaxf(bv.w + u0 * w0.w + u1 * w1.w, 0.0f);
        *(float4*)(out + i * HID + jb) = o;
    } else if (t < TO4) {
        int q = t - TZ4;
        int i = q >> 4, jb = (q & 15) << 2;
        const float* u = ws + WUO + 4 * i;
        float u0 = u[0], u1 = u[1], u2 = u[2];
        float4 w0 = *(const float4*)(Wo + jb);
        float4 w1 = *(const float4*)(Wo + HID + jb);
        float4 w2 = *(const float4*)(Wo + 2 * HID + jb);
        float4 bv = *(const float4*)(bo + jb);
        float4 o;
        o.x = fmaxf(bv.x + u0 * w0.x + u1 * w1.x + u2 * w2.x, 0.0f);
        o.y = fmaxf(bv.y + u0 * w0.y + u1 * w1.y + u2 * w2.y, 0.0f);
        o.z = fmaxf(bv.z + u0 * w0.z + u1 * w1.z + u2 * w2.z, 0.0f);
        o.w = fmaxf(bv.w + u0 * w0.w + u1 * w1.w + u2 * w2.w, 0.0f);
        *(float4*)(out + N_ZONE * HID + i * HID + jb) = o;
    } else if (t < TG4) {
        int q = t - TO4;
        int i = q >> 4, jb = (q & 15) << 2;
        float u0 = ws[WUG + i];
        float4 w0 = *(const float4*)(Wg + jb);
        float4 bv = *(const float4*)(bg + jb);
        float4 o;
        o.x = fmaxf(bv.x + u0 * w0.x, 0.0f);
        o.y = fmaxf(bv.y + u0 * w0.y, 0.0f);
        o.z = fmaxf(bv.z + u0 * w0.z, 0.0f);
        o.w = fmaxf(bv.w + u0 * w0.w, 0.0f);
        *(float4*)(out + (N_ZONE + N_OUT) * HID + i * HID + jb) = o;
    }
}

// ---------------- fallback path (proven R1 kernels, 2.4 MB ws) ----------------
#define F_DEG_Z   0
#define F_DEG_O   (N_ZONE)
#define F_DEG_G   (N_ZONE + N_OUT)
#define F_DEG_TOT N_TOT
#define F_S_Z     F_DEG_TOT
#define F_S_O     (F_S_Z + N_ZONE * 2)
#define F_S_G     (F_S_O + N_OUT * 3)
#define F_TOT     (F_S_G + N_GND * 1)

__global__ void f_init(float* __restrict__ ws) {
    int i = blockIdx.x * blockDim.x + threadIdx.x;
    if (i < F_TOT) ws[i] = (i < F_DEG_TOT) ? 1.0f : 0.0f;
}
__global__ void f_deg(const int* __restrict__ eiz, const float* __restrict__ wz,
                      const int* __restrict__ eio, const float* __restrict__ wo,
                      const int* __restrict__ eig, const float* __restrict__ wg,
                      float* __restrict__ ws) {
    int t = blockIdx.x * blockDim.x + threadIdx.x;
    if (t < E_ZONE) atomicAdd(ws + F_DEG_Z + eiz[E_ZONE + t], wz[t]);
    else if (t < E_ZONE + E_OUT) { int e = t - E_ZONE; atomicAdd(ws + F_DEG_O + eio[E_OUT + e], wo[e]); }
    else if (t < E_ZONE + E_OUT + E_GND) { int e = t - E_ZONE - E_OUT; atomicAdd(ws + F_DEG_G + eig[E_GND + e], wg[e]); }
}
__global__ void f_dinv(float* __restrict__ ws) {
    int i = blockIdx.x * blockDim.x + threadIdx.x;
    if (i < F_DEG_TOT) ws[i] = 1.0f / sqrtf(ws[i]);
}
__global__ void f_scatter(const int* __restrict__ eiz, const float* __restrict__ wz, const float* __restrict__ xz,
                          const int* __restrict__ eio, const float* __restrict__ wo, const float* __restrict__ xo,
                          const int* __restrict__ eig, const float* __restrict__ wg, const float* __restrict__ xg,
                          float* __restrict__ ws) {
    int t = blockIdx.x * blockDim.x + threadIdx.x;
    if (t < E_ZONE) {
        int row = eiz[t], col = eiz[E_ZONE + t];
        float n = ws[F_DEG_Z + row] * wz[t] * ws[F_DEG_Z + col];
        atomicAdd(ws + F_S_Z + col * 2 + 0, n * xz[row * 2 + 0]);
        atomicAdd(ws + F_S_Z + col * 2 + 1, n * xz[row * 2 + 1]);
    } else if (t < E_ZONE + E_OUT) {
        int e = t - E_ZONE;
        int row = eio[e], col = eio[E_OUT + e];
        float n = ws[F_DEG_O + row] * wo[e] * ws[F_DEG_O + col];
        atomicAdd(ws + F_S_O + col * 3 + 0, n * xo[row * 3 + 0]);
        atomicAdd(ws + F_S_O + col * 3 + 1, n * xo[row * 3 + 1]);
        atomicAdd(ws + F_S_O + col * 3 + 2, n * xo[row * 3 + 2]);
    } else if (t < E_ZONE + E_OUT + E_GND) {
        int e = t - E_ZONE - E_OUT;
        int row = eig[e], col = eig[E_GND + e];
        float n = ws[F_DEG_G + row] * wg[e] * ws[F_DEG_G + col];
        atomicAdd(ws + F_S_G + col, n * xg[row]);
    }
}
__global__ void f_final(const float* __restrict__ ws,
                        const float* __restrict__ xz, const float* __restrict__ Wz, const float* __restrict__ bz,
                        const float* __restrict__ xo, const float* __restrict__ Wo, const float* __restrict__ bo,
                        const float* __restrict__ xg, const float* __restrict__ Wg, const float* __restrict__ bg,
                        float* __restrict__ out) {
    int t = blockIdx.x * blockDim.x + threadIdx.x;
    const int TZ = N_ZONE * HID, TO = TZ + N_OUT * HID, TG = TO + N_GND * HID;
    if (t < TZ) {
        int i = t >> 6, j = t & 63;
        float di = ws[F_DEG_Z + i], d2 = di * di;
        float t0 = ws[F_S_Z + i * 2 + 0] + d2 * xz[i * 2 + 0];
        float t1 = ws[F_S_Z + i * 2 + 1] + d2 * xz[i * 2 + 1];
        out[t] = fmaxf(bz[j] + t0 * Wz[j] + t1 * Wz[HID + j], 0.0f);
    } else if (t < TO) {
        int u = t - TZ;
        int i = u >> 6, j = u & 63;
        float di = ws[F_DEG_O + i], d2 = di * di;
        float t0 = ws[F_S_O + i * 3 + 0] + d2 * xo[i * 3 + 0];
        float t1 = ws[F_S_O + i * 3 + 1] + d2 * xo[i * 3 + 1];
        float t2 = ws[F_S_O + i * 3 + 2] + d2 * xo[i * 3 + 2];
        out[t] = fmaxf(bo[j] + t0 * Wo[j] + t1 * Wo[HID + j] + t2 * Wo[2 * HID + j], 0.0f);
    } else if (t < TG) {
        int u = t - TO;
        int i = u >> 6, j = u & 63;
        float di = ws[F_DEG_G + i], d2 = di * di;
        float t0 = ws[F_S_G + i] + d2 * xg[i];
        out[t] = fmaxf(bg[j] + t0 * Wg[j], 0.0f);
    }
}

extern "C" void kernel_launch(void* const* d_in, const int* in_sizes, int n_in,
                              void* d_out, int out_size, void* d_ws, size_t ws_size,
                              hipStream_t stream) {
    const float* xz = (const float*)d_in[0];
    const float* xo = (const float*)d_in[1];
    const float* xg = (const float*)d_in[2];
    const int*  eiz = (const int*)d_in[3];
    const int*  eio = (const int*)d_in[4];
    const int*  eig = (const int*)d_in[5];
    const float* Wz = (const float*)d_in[6];
    const float* Wo = (const float*)d_in[7];
    const float* Wg = (const float*)d_in[8];
    const float* bz = (const float*)d_in[9];
    const float* bo = (const float*)d_in[10];
    const float* bg = (const float*)d_in[11];
    const float* wz = (const float*)d_in[12];
    const float* wo = (const float*)d_in[13];
    const float* wg = (const float*)d_in[14];
    float* out = (float*)d_out;
    float* ws  = (float*)d_ws;

    const int B = 256;

    if (ws_size >= FAST_WS_BYTES) {
        unsigned* cur = (unsigned*)(ws + WCUR);
        uint2* rec = (uint2*)(ws + WREC);
        hipMemsetAsync(cur, 0, 128 * 4, stream);
        k_bin<<<NCHUNK, B, 0, stream>>>(eiz, wz, eio, wo, eig, wg, cur, rec);
        k_degp<<<NBUCKET * SL, B, 0, stream>>>(rec, cur, ws + WPDEG);
        k_dinvy<<<(PAD_TOT + B - 1) / B, B, 0, stream>>>(xz, xo, xg, ws);
        k_sp<<<NBUCKET * SL, B, 0, stream>>>(ws);
        k_u<<<(PAD_TOT + B - 1) / B, B, 0, stream>>>(ws);
        k_fin2<<<(N_TOT * HID / 4 + B - 1) / B, B, 0, stream>>>(ws, Wz, bz, Wo, bo, Wg, bg, out);
    } else {
        const int E_TOT = E_TOTAL, OUT_TOT = N_TOT * HID;
        f_init<<<(F_TOT + B - 1) / B, B, 0, stream>>>(ws);
        f_deg<<<(E_TOT + B - 1) / B, B, 0, stream>>>(eiz, wz, eio, wo, eig, wg, ws);
        f_dinv<<<(F_DEG_TOT + B - 1) / B, B, 0, stream>>>(ws);
        f_scatter<<<(E_TOT + B - 1) / B, B, 0, stream>>>(eiz, wz, xz, eio, wo, xo, eig, wg, xg, ws);
        f_final<<<(OUT_TOT + B - 1) / B, B, 0, stream>>>(ws, xz, Wz, bz, xo, Wo, bo, xg, Wg, bg, out);
    }
}

// Round 6
// 246.223 us; speedup vs baseline: 1.7217x; 1.0100x over previous
//
#include <hip/hip_runtime.h>

#define N_ZONE 100000
#define E_ZONE 2000000
#define N_OUT  50000
#define E_OUT  1000000
#define N_GND  50000
#define E_GND  1000000
#define HID    64
#define N_TOT   (N_ZONE + N_OUT + N_GND)     // 200000
#define E_TOTAL (E_ZONE + E_OUT + E_GND)     // 4000000

// ---- binning geometry ----
#define RANGE   2048
#define RSHIFT  11
#define NBZ     49
#define NBO     25
#define NBG     25
#define NBUCKET (NBZ + NBO + NBG)            // 99
#define SL      16                           // slices per bucket
#define CAP     49152                        // fixed bucket capacity (mean ~40.6k, sigma ~200)
#define OUT_PAD_BASE (NBZ * RANGE)           // 100352
#define GND_PAD_BASE ((NBZ + NBO) * RANGE)   // 151552
#define PAD_TOT      (NBUCKET * RANGE)       // 202752

#define CHUNK  4096
#define NCHUNK ((E_TOTAL + CHUNK - 1) / CHUNK)   // 977

// ILP batch depth for record loops
#define KUF 8

// ---- ws layout (32-bit words), no overlays ----
#define WCUR  0                               // u32 CUR[128] (bucket fill counts)
#define WREC  128                             // uint2 rec[99*CAP]
#define WPDEG (WREC + 2 * NBUCKET * CAP)      // 99*16*2048 deg partials (16 slices)
#define WPSZ  (WPDEG + NBUCKET * SL * RANGE)
#define WPSO  (WPSZ + NBZ * SL * RANGE * 2)
#define WPSG  (WPSO + NBO * SL * RANGE * 3)
#define WDINV (WPSG + NBG * SL * RANGE)
#define WYZ   (WDINV + PAD_TOT)
#define WYO   (WYZ + 2 * N_ZONE)
#define WYG   (WYO + 4 * N_OUT)
#define WUZ   (WYG + N_GND)
#define WUO   (WUZ + 2 * N_ZONE)
#define WUG   (WUO + 4 * N_OUT)
#define WTOT  (WUG + N_GND)                   // 20,567,072 words = 82.3 MB
#define FAST_WS_BYTES ((size_t)WTOT * 4)

// K1: single-pass bin: stage chunk in LDS ordered by bucket, bump-allocate into
// fixed-CAP bucket regions, direct-lookup copy-out (bucket id staged per slot).
__global__ void k_bin(const int* __restrict__ eiz, const float* __restrict__ wz,
                      const int* __restrict__ eio, const float* __restrict__ wo,
                      const int* __restrict__ eig, const float* __restrict__ wg,
                      unsigned* __restrict__ cur, uint2* __restrict__ rec) {
    __shared__ unsigned la[CHUNK];
    __shared__ float    lw[CHUNK];
    __shared__ unsigned char lbk[CHUNK];
    __shared__ unsigned hist[NBUCKET];
    __shared__ unsigned sbase[NBUCKET + 1];
    __shared__ unsigned gbase[NBUCKET];
    int tid = threadIdx.x;
    for (int b = tid; b < NBUCKET; b += 256) hist[b] = 0;
    __syncthreads();
    int t0 = blockIdx.x * CHUNK;
    unsigned mya[CHUNK / 256], mybk[CHUNK / 256], myr[CHUNK / 256];
    float myw[CHUNK / 256];
#pragma unroll
    for (int i = 0; i < CHUNK / 256; i++) {
        int t = t0 + i * 256 + tid;
        unsigned b = 0xFFFFFFFFu;
        if (t < E_TOTAL) {
            int row, col; float w;
            if (t < E_ZONE) { row = eiz[t]; col = eiz[E_ZONE + t]; w = wz[t]; b = col >> RSHIFT; }
            else if (t < E_ZONE + E_OUT) { int e = t - E_ZONE; row = eio[e]; col = eio[E_OUT + e]; w = wo[e]; b = NBZ + (col >> RSHIFT); }
            else { int e = t - E_ZONE - E_OUT; row = eig[e]; col = eig[E_GND + e]; w = wg[e]; b = NBZ + NBO + (col >> RSHIFT); }
            mya[i] = ((unsigned)(col & (RANGE - 1)) << 17) | (unsigned)row;
            myw[i] = w;
            myr[i] = atomicAdd(&hist[b], 1u);
        }
        mybk[i] = b;
    }
    __syncthreads();
    if (tid == 0) {
        unsigned acc = 0;
        for (int b = 0; b < NBUCKET; b++) { sbase[b] = acc; acc += hist[b]; }
        sbase[NBUCKET] = acc;
    }
    __syncthreads();
    if (tid < NBUCKET)
        gbase[tid] = hist[tid] ? atomicAdd(&cur[tid], hist[tid]) : 0u;
#pragma unroll
    for (int i = 0; i < CHUNK / 256; i++) {
        if (mybk[i] < NBUCKET) {
            unsigned p = sbase[mybk[i]] + myr[i];
            la[p] = mya[i]; lw[p] = myw[i];
            lbk[p] = (unsigned char)mybk[i];
        }
    }
    __syncthreads();
    unsigned total = sbase[NBUCKET];
    unsigned p = tid;
    for (; p + 768u < total; p += 1024u) {
#pragma unroll
        for (int u = 0; u < 4; u++) {
            unsigned pp = p + 256u * u;
            unsigned b = lbk[pp];
            unsigned idx = b * CAP + gbase[b] + (pp - sbase[b]);
            rec[idx] = make_uint2(la[pp], __float_as_uint(lw[pp]));
        }
    }
    for (; p < total; p += 256u) {
        unsigned b = lbk[p];
        unsigned idx = b * CAP + gbase[b] + (p - sbase[b]);
        rec[idx] = make_uint2(la[p], __float_as_uint(lw[p]));
    }
}

// K2: per (bucket, slice): LDS-accumulate deg, write dense partial.
__global__ void k_degp(const uint2* __restrict__ rec, const unsigned* __restrict__ cur,
                       float* __restrict__ pdeg) {
    __shared__ float deg[RANGE];
    int r = blockIdx.x / SL, sl = blockIdx.x % SL, tid = threadIdx.x;
    for (int i = tid; i < RANGE; i += 256) deg[i] = 0.0f;
    __syncthreads();
    unsigned c = cur[r];
    size_t b0 = (size_t)r * CAP;
    unsigned per = (c + SL - 1) / SL;
    unsigned s0 = sl * per, s1 = s0 + per; if (s1 > c) s1 = c;
    unsigned j = s0 + tid;
    for (; j + 256u * (KUF - 1) < s1; j += 256u * KUF) {
        uint2 q[KUF];
#pragma unroll
        for (int u = 0; u < KUF; u++) q[u] = rec[b0 + j + 256u * u];
#pragma unroll
        for (int u = 0; u < KUF; u++)
            atomicAdd(&deg[(q[u].x >> 17) & (RANGE - 1)], __uint_as_float(q[u].y));
    }
    for (; j < s1; j += 256u) {
        uint2 q = rec[b0 + j];
        atomicAdd(&deg[(q.x >> 17) & (RANGE - 1)], __uint_as_float(q.y));
    }
    __syncthreads();
    float* o = pdeg + (size_t)blockIdx.x * RANGE;
    for (int i = tid * 4; i < RANGE; i += 1024)
        *(float4*)&o[i] = *(float4*)&deg[i];
}

// K3: reduce deg partials -> dinv; y = dinv * x
__global__ void k_dinvy(const float* __restrict__ xz, const float* __restrict__ xo,
                        const float* __restrict__ xg, float* __restrict__ ws) {
    int p = blockIdx.x * blockDim.x + threadIdx.x;
    if (p >= PAD_TOT) return;
    int r = p >> RSHIFT, i = p & (RANGE - 1);
    float d = 1.0f;
#pragma unroll
    for (int sl = 0; sl < SL; sl++)
        d += ws[WPDEG + (size_t)(r * SL + sl) * RANGE + i];
    float di = rsqrtf(d);
    ws[WDINV + p] = di;
    if (p < OUT_PAD_BASE) {
        if (p < N_ZONE) {
            ws[WYZ + 2 * p]     = di * xz[2 * p];
            ws[WYZ + 2 * p + 1] = di * xz[2 * p + 1];
        }
    } else if (p < GND_PAD_BASE) {
        int idx = p - OUT_PAD_BASE;
        if (idx < N_OUT) {
            ws[WYO + 4 * idx]     = di * xo[3 * idx];
            ws[WYO + 4 * idx + 1] = di * xo[3 * idx + 1];
            ws[WYO + 4 * idx + 2] = di * xo[3 * idx + 2];
            ws[WYO + 4 * idx + 3] = 0.0f;
        }
    } else {
        int idx = p - GND_PAD_BASE;
        if (idx < N_GND) ws[WYG + idx] = di * xg[idx];
    }
}

// K4: per (bucket, slice): LDS-accumulate s += w*y[row], planar layout.
// Tag-count reduction round: out-gather is ONE float4 (16B, 1 request) instead
// of two 8B requests; remainder loads exec-masked (no clamped dummy requests).
// Scattered request count 5M -> 4M: clean test of the MSHR/tag-cap theory.
__global__ void k_sp(float* __restrict__ ws) {
    __shared__ __align__(16) float s[RANGE * 3];     // 24 KB
    int r = blockIdx.x / SL, sl = blockIdx.x % SL, tid = threadIdx.x;
    const unsigned* cur = (const unsigned*)(ws + WCUR);
    const uint2* rec = (const uint2*)(ws + WREC);
    int ch, rg; size_t yoff, psoff;
    if (r < NBZ)            { ch = 2; rg = r;             yoff = WYZ; psoff = WPSZ; }
    else if (r < NBZ + NBO) { ch = 3; rg = r - NBZ;       yoff = WYO; psoff = WPSO; }
    else                    { ch = 1; rg = r - NBZ - NBO; yoff = WYG; psoff = WPSG; }
    int tot = RANGE * ch;
    for (int i = tid; i < tot; i += 256) s[i] = 0.0f;
    __syncthreads();
    unsigned c = cur[r];
    size_t b0 = (size_t)r * CAP;
    unsigned per = (c + SL - 1) / SL;
    unsigned s0 = sl * per, s1 = s0 + per; if (s1 > c) s1 = c;
    if (ch == 2) {
        const float2* y = (const float2*)(ws + yoff);
        unsigned j = s0 + tid;
        for (; j + 256u * (KUF - 1) < s1; j += 256u * KUF) {
            uint2 q[KUF];
#pragma unroll
            for (int u = 0; u < KUF; u++) q[u] = rec[b0 + j + 256u * u];
            float2 yv[KUF];
#pragma unroll
            for (int u = 0; u < KUF; u++) yv[u] = y[q[u].x & 0x1FFFFu];
#pragma unroll
            for (int u = 0; u < KUF; u++) {
                unsigned colr = (q[u].x >> 17) & (RANGE - 1);
                float w = __uint_as_float(q[u].y);
                atomicAdd(&s[colr],         w * yv[u].x);
                atomicAdd(&s[RANGE + colr], w * yv[u].y);
            }
        }
        for (; j < s1; j += 256u) {
            uint2 q = rec[b0 + j];
            float2 yv = y[q.x & 0x1FFFFu];
            unsigned colr = (q.x >> 17) & (RANGE - 1);
            float w = __uint_as_float(q.y);
            atomicAdd(&s[colr],         w * yv.x);
            atomicAdd(&s[RANGE + colr], w * yv.y);
        }
    } else if (ch == 3) {
        const float4* y = (const float4*)(ws + yoff);
        unsigned j = s0 + tid;
        for (; j + 256u * (KUF - 1) < s1; j += 256u * KUF) {
            uint2 q[KUF];
#pragma unroll
            for (int u = 0; u < KUF; u++) q[u] = rec[b0 + j + 256u * u];
            float4 yv[KUF];
#pragma unroll
            for (int u = 0; u < KUF; u++) yv[u] = y[q[u].x & 0x1FFFFu];   // single 16B request
#pragma unroll
            for (int u = 0; u < KUF; u++) {
                unsigned colr = (q[u].x >> 17) & (RANGE - 1);
                float w = __uint_as_float(q[u].y);
                atomicAdd(&s[colr],             w * yv[u].x);
                atomicAdd(&s[RANGE + colr],     w * yv[u].y);
                atomicAdd(&s[2 * RANGE + colr], w * yv[u].z);
            }
        }
        for (; j < s1; j += 256u) {
            uint2 q = rec[b0 + j];
            float4 yv = y[q.x & 0x1FFFFu];
            unsigned colr = (q.x >> 17) & (RANGE - 1);
            float w = __uint_as_float(q.y);
            atomicAdd(&s[colr],             w * yv.x);
            atomicAdd(&s[RANGE + colr],     w * yv.y);
            atomicAdd(&s[2 * RANGE + colr], w * yv.z);
        }
    } else {
        const float* y = ws + yoff;
        unsigned j = s0 + tid;
        for (; j + 256u * (KUF - 1) < s1; j += 256u * KUF) {
            uint2 q[KUF];
#pragma unroll
            for (int u = 0; u < KUF; u++) q[u] = rec[b0 + j + 256u * u];
            float yv[KUF];
#pragma unroll
            for (int u = 0; u < KUF; u++) yv[u] = y[q[u].x & 0x1FFFFu];
#pragma unroll
            for (int u = 0; u < KUF; u++)
                atomicAdd(&s[(q[u].x >> 17) & (RANGE - 1)], __uint_as_float(q[u].y) * yv[u]);
        }
        for (; j < s1; j += 256u) {
            uint2 q = rec[b0 + j];
            atomicAdd(&s[(q.x >> 17) & (RANGE - 1)], __uint_as_float(q.y) * y[q.x & 0x1FFFFu]);
        }
    }
    __syncthreads();
    float* o = ws + psoff + (size_t)(rg * SL + sl) * tot;
    for (int i = tid * 4; i < tot; i += 1024)
        *(float4*)&o[i] = *(float4*)&s[i];
}

// K5: u = dinv * (y + sum_slices partial_s)  — reads match k_sp's planar layout
__global__ void k_u(float* __restrict__ ws) {
    int p = blockIdx.x * blockDim.x + threadIdx.x;
    if (p >= PAD_TOT) return;
    int r = p >> RSHIFT, i = p & (RANGE - 1);
    float di = ws[WDINV + p];
    if (p < OUT_PAD_BASE) {
        if (p >= N_ZONE) return;
        float s0 = ws[WYZ + 2 * p], s1 = ws[WYZ + 2 * p + 1];
#pragma unroll
        for (int sl = 0; sl < SL; sl++) {
            const float* ps = ws + WPSZ + (size_t)(r * SL + sl) * RANGE * 2;
            s0 += ps[i]; s1 += ps[RANGE + i];
        }
        ws[WUZ + 2 * p] = di * s0; ws[WUZ + 2 * p + 1] = di * s1;
    } else if (p < GND_PAD_BASE) {
        int idx = p - OUT_PAD_BASE;
        if (idx >= N_OUT) return;
        int rg = r - NBZ;
        float s0 = ws[WYO + 4 * idx], s1 = ws[WYO + 4 * idx + 1], s2 = ws[WYO + 4 * idx + 2];
#pragma unroll
        for (int sl = 0; sl < SL; sl++) {
            const float* ps = ws + WPSO + (size_t)(rg * SL + sl) * RANGE * 3;
            s0 += ps[i]; s1 += ps[RANGE + i]; s2 += ps[2 * RANGE + i];
        }
        ws[WUO + 4 * idx] = di * s0; ws[WUO + 4 * idx + 1] = di * s1; ws[WUO + 4 * idx + 2] = di * s2;
    } else {
        int idx = p - GND_PAD_BASE;
        if (idx >= N_GND) return;
        int rg = r - NBZ - NBO;
        float s0 = ws[WYG + idx];
#pragma unroll
        for (int sl = 0; sl < SL; sl++)
            s0 += ws[WPSG + (size_t)(rg * SL + sl) * RANGE + i];
        ws[WUG + idx] = di * s0;
    }
}

// K6: out = relu(u @ W + b), float4 stores
__global__ void k_fin2(const float* __restrict__ ws,
                       const float* __restrict__ Wz, const float* __restrict__ bz,
                       const float* __restrict__ Wo, const float* __restrict__ bo,
                       const float* __restrict__ Wg, const float* __restrict__ bg,
                       float* __restrict__ out) {
    int t = blockIdx.x * blockDim.x + threadIdx.x;
    const int TZ4 = N_ZONE * 16, TO4 = TZ4 + N_OUT * 16, TG4 = TO4 + N_GND * 16;
    if (t < TZ4) {
        int i = t >> 4, jb = (t & 15) << 2;
        float u0 = ws[WUZ + 2 * i], u1 = ws[WUZ + 2 * i + 1];
        float4 w0 = *(const float4*)(Wz + jb);
        float4 w1 = *(const float4*)(Wz + HID + jb);
        float4 bv = *(const float4*)(bz + jb);
        float4 o;
        o.x = fmaxf(bv.x + u0 * w0.x + u1 * w1.x, 0.0f);
        o.y = fmaxf(bv.y + u0 * w0.y + u1 * w1.y, 0.0f);
        o.z = fmaxf(bv.z + u0 * w0.z + u1 * w1.z, 0.0f);
        o.w = fmaxf(bv.w + u0 * w0.w + u1 * w1.w, 0.0f);
        *(float4*)(out + i * HID + jb) = o;
    } else if (t < TO4) {
        int q = t - TZ4;
        int i = q >> 4, jb = (q & 15) << 2;
        const float* u = ws + WUO + 4 * i;
        float u0 = u[0], u1 = u[1], u2 = u[2];
        float4 w0 = *(const float4*)(Wo + jb);
        float4 w1 = *(const float4*)(Wo + HID + jb);
        float4 w2 = *(const float4*)(Wo + 2 * HID + jb);
        float4 bv = *(const float4*)(bo + jb);
        float4 o;
        o.x = fmaxf(bv.x + u0 * w0.x + u1 * w1.x + u2 * w2.x, 0.0f);
        o.y = fmaxf(bv.y + u0 * w0.y + u1 * w1.y + u2 * w2.y, 0.0f);
        o.z = fmaxf(bv.z + u0 * w0.z + u1 * w1.z + u2 * w2.z, 0.0f);
        o.w = fmaxf(bv.w + u0 * w0.w + u1 * w1.w + u2 * w2.w, 0.0f);
        *(float4*)(out + N_ZONE * HID + i * HID + jb) = o;
    } else if (t < TG4) {
        int q = t - TO4;
        int i = q >> 4, jb = (q & 15) << 2;
        float u0 = ws[WUG + i];
        float4 w0 = *(const float4*)(Wg + jb);
        float4 bv = *(const float4*)(bg + jb);
        float4 o;
        o.x = fmaxf(bv.x + u0 * w0.x, 0.0f);
        o.y = fmaxf(bv.y + u0 * w0.y, 0.0f);
        o.z = fmaxf(bv.z + u0 * w0.z, 0.0f);
        o.w = fmaxf(bv.w + u0 * w0.w, 0.0f);
        *(float4*)(out + (N_ZONE + N_OUT) * HID + i * HID + jb) = o;
    }
}

// ---------------- fallback path (proven R1 kernels, 2.4 MB ws) ----------------
#define F_DEG_Z   0
#define F_DEG_O   (N_ZONE)
#define F_DEG_G   (N_ZONE + N_OUT)
#define F_DEG_TOT N_TOT
#define F_S_Z     F_DEG_TOT
#define F_S_O     (F_S_Z + N_ZONE * 2)
#define F_S_G     (F_S_O + N_OUT * 3)
#define F_TOT     (F_S_G + N_GND * 1)

__global__ void f_init(float* __restrict__ ws) {
    int i = blockIdx.x * blockDim.x + threadIdx.x;
    if (i < F_TOT) ws[i] = (i < F_DEG_TOT) ? 1.0f : 0.0f;
}
__global__ void f_deg(const int* __restrict__ eiz, const float* __restrict__ wz,
                      const int* __restrict__ eio, const float* __restrict__ wo,
                      const int* __restrict__ eig, const float* __restrict__ wg,
                      float* __restrict__ ws) {
    int t = blockIdx.x * blockDim.x + threadIdx.x;
    if (t < E_ZONE) atomicAdd(ws + F_DEG_Z + eiz[E_ZONE + t], wz[t]);
    else if (t < E_ZONE + E_OUT) { int e = t - E_ZONE; atomicAdd(ws + F_DEG_O + eio[E_OUT + e], wo[e]); }
    else if (t < E_ZONE + E_OUT + E_GND) { int e = t - E_ZONE - E_OUT; atomicAdd(ws + F_DEG_G + eig[E_GND + e], wg[e]); }
}
__global__ void f_dinv(float* __restrict__ ws) {
    int i = blockIdx.x * blockDim.x + threadIdx.x;
    if (i < F_DEG_TOT) ws[i] = 1.0f / sqrtf(ws[i]);
}
__global__ void f_scatter(const int* __restrict__ eiz, const float* __restrict__ wz, const float* __restrict__ xz,
                          const int* __restrict__ eio, const float* __restrict__ wo, const float* __restrict__ xo,
                          const int* __restrict__ eig, const float* __restrict__ wg, const float* __restrict__ xg,
                          float* __restrict__ ws) {
    int t = blockIdx.x * blockDim.x + threadIdx.x;
    if (t < E_ZONE) {
        int row = eiz[t], col = eiz[E_ZONE + t];
        float n = ws[F_DEG_Z + row] * wz[t] * ws[F_DEG_Z + col];
        atomicAdd(ws + F_S_Z + col * 2 + 0, n * xz[row * 2 + 0]);
        atomicAdd(ws + F_S_Z + col * 2 + 1, n * xz[row * 2 + 1]);
    } else if (t < E_ZONE + E_OUT) {
        int e = t - E_ZONE;
        int row = eio[e], col = eio[E_OUT + e];
        float n = ws[F_DEG_O + row] * wo[e] * ws[F_DEG_O + col];
        atomicAdd(ws + F_S_O + col * 3 + 0, n * xo[row * 3 + 0]);
        atomicAdd(ws + F_S_O + col * 3 + 1, n * xo[row * 3 + 1]);
        atomicAdd(ws + F_S_O + col * 3 + 2, n * xo[row * 3 + 2]);
    } else if (t < E_ZONE + E_OUT + E_GND) {
        int e = t - E_ZONE - E_OUT;
        int row = eig[e], col = eig[E_GND + e];
        float n = ws[F_DEG_G + row] * wg[e] * ws[F_DEG_G + col];
        atomicAdd(ws + F_S_G + col, n * xg[row]);
    }
}
__global__ void f_final(const float* __restrict__ ws,
                        const float* __restrict__ xz, const float* __restrict__ Wz, const float* __restrict__ bz,
                        const float* __restrict__ xo, const float* __restrict__ Wo, const float* __restrict__ bo,
                        const float* __restrict__ xg, const float* __restrict__ Wg, const float* __restrict__ bg,
                        float* __restrict__ out) {
    int t = blockIdx.x * blockDim.x + threadIdx.x;
    const int TZ = N_ZONE * HID, TO = TZ + N_OUT * HID, TG = TO + N_GND * HID;
    if (t < TZ) {
        int i = t >> 6, j = t & 63;
        float di = ws[F_DEG_Z + i], d2 = di * di;
        float t0 = ws[F_S_Z + i * 2 + 0] + d2 * xz[i * 2 + 0];
        float t1 = ws[F_S_Z + i * 2 + 1] + d2 * xz[i * 2 + 1];
        out[t] = fmaxf(bz[j] + t0 * Wz[j] + t1 * Wz[HID + j], 0.0f);
    } else if (t < TO) {
        int u = t - TZ;
        int i = u >> 6, j = u & 63;
        float di = ws[F_DEG_O + i], d2 = di * di;
        float t0 = ws[F_S_O + i * 3 + 0] + d2 * xo[i * 3 + 0];
        float t1 = ws[F_S_O + i * 3 + 1] + d2 * xo[i * 3 + 1];
        float t2 = ws[F_S_O + i * 3 + 2] + d2 * xo[i * 3 + 2];
        out[t] = fmaxf(bo[j] + t0 * Wo[j] + t1 * Wo[HID + j] + t2 * Wo[2 * HID + j], 0.0f);
    } else if (t < TG) {
        int u = t - TO;
        int i = u >> 6, j = u & 63;
        float di = ws[F_DEG_G + i], d2 = di * di;
        float t0 = ws[F_S_G + i] + d2 * xg[i];
        out[t] = fmaxf(bg[j] + t0 * Wg[j], 0.0f);
    }
}

extern "C" void kernel_launch(void* const* d_in, const int* in_sizes, int n_in,
                              void* d_out, int out_size, void* d_ws, size_t ws_size,
                              hipStream_t stream) {
    const float* xz = (const float*)d_in[0];
    const float* xo = (const float*)d_in[1];
    const float* xg = (const float*)d_in[2];
    const int*  eiz = (const int*)d_in[3];
    const int*  eio = (const int*)d_in[4];
    const int*  eig = (const int*)d_in[5];
    const float* Wz = (const float*)d_in[6];
    const float* Wo = (const float*)d_in[7];
    const float* Wg = (const float*)d_in[8];
    const float* bz = (const float*)d_in[9];
    const float* bo = (const float*)d_in[10];
    const float* bg = (const float*)d_in[11];
    const float* wz = (const float*)d_in[12];
    const float* wo = (const float*)d_in[13];
    const float* wg = (const float*)d_in[14];
    float* out = (float*)d_out;
    float* ws  = (float*)d_ws;

    const int B = 256;

    if (ws_size >= FAST_WS_BYTES) {
        unsigned* cur = (unsigned*)(ws + WCUR);
        uint2* rec = (uint2*)(ws + WREC);
        hipMemsetAsync(cur, 0, 128 * 4, stream);
        k_bin<<<NCHUNK, B, 0, stream>>>(eiz, wz, eio, wo, eig, wg, cur, rec);
        k_degp<<<NBUCKET * SL, B, 0, stream>>>(rec, cur, ws + WPDEG);
        k_dinvy<<<(PAD_TOT + B - 1) / B, B, 0, stream>>>(xz, xo, xg, ws);
        k_sp<<<NBUCKET * SL, B, 0, stream>>>(ws);
        k_u<<<(PAD_TOT + B - 1) / B, B, 0, stream>>>(ws);
        k_fin2<<<(N_TOT * HID / 4 + B - 1) / B, B, 0, stream>>>(ws, Wz, bz, Wo, bo, Wg, bg, out);
    } else {
        const int E_TOT = E_TOTAL, OUT_TOT = N_TOT * HID;
        f_init<<<(F_TOT + B - 1) / B, B, 0, stream>>>(ws);
        f_deg<<<(E_TOT + B - 1) / B, B, 0, stream>>>(eiz, wz, eio, wo, eig, wg, ws);
        f_dinv<<<(F_DEG_TOT + B - 1) / B, B, 0, stream>>>(ws);
        f_scatter<<<(E_TOT + B - 1) / B, B, 0, stream>>>(eiz, wz, xz, eio, wo, xo, eig, wg, xg, ws);
        f_final<<<(OUT_TOT + B - 1) / B, B, 0, stream>>>(ws, xz, Wz, bz, xo, Wo, bo, xg, Wg, bg, out);
    }
}